// Round 2
// baseline (8880.576 us; speedup 1.0000x reference)
//
#include <hip/hip_runtime.h>

// ZOH linear layer: K[1,8192], dim 2048.
// E=expm(.01A)-I (Taylor3, 2 f32 GEMMs); ER=expm(1.28A)-I (PS deg-6, 3 f32 GEMMs);
// W=inv(A+1e-3 I) in FULL f64: block-Schur recursion (64-tile f64 GEMM) + pivoted
// f64 GJ 64x64 base + f64 iterative refinement (vector only, 6 iters).
// K[128j+i] = (C*AR^j)·(A^i*Bbar): two serial matvec chains (127 steps) + dots.
// Arena ~96.7MB: Ebuf | t1 t2 (=M64) | t3 t4 (=W64) | scr64 | vectors.

#define DIMN 2048
#define MSTEPS 8192
#define RBLK 128
#define NJROWS 64
#define NN ((size_t)DIMN * DIMN)
// nested Schur scratch: sum h^2 for h = 1024,512,256,128,64 (doubles)
#define SCRD ((size_t)(1024*1024 + 512*512 + 256*256 + 128*128 + 64*64))

// ---------------- elementwise f32: out = c1*i1+c2*i2+c3*i3+c4*i4 + dval*I ----------------
__global__ __launch_bounds__(256)
void k_combine4(float* out,
                const float* i1, float c1, const float* i2, float c2,
                const float* i3, float c3, const float* i4, float c4,
                float dval)
{
  const int total = DIMN * DIMN;
  for (int idx = blockIdx.x * 256 + threadIdx.x; idx < total; idx += gridDim.x * 256) {
    float v = 0.f;
    if (i1) v = fmaf(c1, i1[idx], v);
    if (i2) v = fmaf(c2, i2[idx], v);
    if (i3) v = fmaf(c3, i3[idx], v);
    if (i4) v = fmaf(c4, i4[idx], v);
    if ((idx >> 11) == (idx & 2047)) v += dval;
    out[idx] = v;
  }
}

// ---------------- M64 = (double)A + 1e-3 I ----------------
__global__ __launch_bounds__(256)
void k_fill64(const float* __restrict__ A, double* __restrict__ M)
{
  const int total = DIMN * DIMN;
  for (int idx = blockIdx.x * 256 + threadIdx.x; idx < total; idx += gridDim.x * 256) {
    double v = (double)A[idx];
    if ((idx >> 11) == (idx & 2047)) v += 1e-3;
    M[idx] = v;
  }
}

// ---------------- f32 GEMM: C = alpha*A*B + c1*E1 + c2*E2 + c3*E3 + dval*I ----------------
#define GBM 128
#define GBN 128
#define GBK 8
__global__ __launch_bounds__(256)
void k_gemm(const float* __restrict__ A, int lda,
            const float* __restrict__ B, int ldb,
            float* C, int ldc, int K, float alpha,
            const float* E1, int ld1, float c1,
            const float* E2, int ld2, float c2,
            const float* E3, int ld3, float c3,
            float dval)
{
  __shared__ float As[GBK][GBM];
  __shared__ float Bs[GBK][GBN];
  const int tid = threadIdx.x;
  const int tx = tid & 15, ty = tid >> 4;
  const int brow = blockIdx.y * GBM, bcol = blockIdx.x * GBN;

  const int arow = tid >> 1, ac0 = (tid & 1) * 4;   // A tile 128x8
  const int brw  = tid >> 5, bc0 = (tid & 31) * 4;  // B tile 8x128

  const float* Aptr = A + (size_t)(brow + arow) * lda + ac0;
  const float* Bptr = B + (size_t)brw * ldb + (bcol + bc0);

  float4 aPre = *(const float4*)Aptr;
  float4 bPre = *(const float4*)Bptr;

  float acc[8][8];
#pragma unroll
  for (int i = 0; i < 8; ++i)
#pragma unroll
    for (int j = 0; j < 8; ++j) acc[i][j] = 0.f;

  const int nk = K / GBK;
  for (int kt = 0; kt < nk; ++kt) {
    As[ac0 + 0][arow] = aPre.x;
    As[ac0 + 1][arow] = aPre.y;
    As[ac0 + 2][arow] = aPre.z;
    As[ac0 + 3][arow] = aPre.w;
    *(float4*)&Bs[brw][bc0] = bPre;
    __syncthreads();
    if (kt + 1 < nk) {
      aPre = *(const float4*)(Aptr + (size_t)(kt + 1) * GBK);
      bPre = *(const float4*)(Bptr + (size_t)(kt + 1) * GBK * ldb);
    }
#pragma unroll
    for (int kk = 0; kk < GBK; ++kk) {
      float a[8], b[8];
      *(float4*)&a[0] = *(const float4*)&As[kk][ty * 8];
      *(float4*)&a[4] = *(const float4*)&As[kk][ty * 8 + 4];
      *(float4*)&b[0] = *(const float4*)&Bs[kk][tx * 8];
      *(float4*)&b[4] = *(const float4*)&Bs[kk][tx * 8 + 4];
#pragma unroll
      for (int i = 0; i < 8; ++i)
#pragma unroll
        for (int j = 0; j < 8; ++j)
          acc[i][j] = fmaf(a[i], b[j], acc[i][j]);
    }
    __syncthreads();
  }
#pragma unroll
  for (int i = 0; i < 8; ++i) {
    const int gi = brow + ty * 8 + i;
#pragma unroll
    for (int j = 0; j < 8; ++j) {
      const int gj = bcol + tx * 8 + j;
      float v = alpha * acc[i][j];
      if (E1) v = fmaf(c1, E1[(size_t)gi * ld1 + gj], v);
      if (E2) v = fmaf(c2, E2[(size_t)gi * ld2 + gj], v);
      if (E3) v = fmaf(c3, E3[(size_t)gi * ld3 + gj], v);
      if (gi == gj) v += dval;
      C[(size_t)gi * ldc + gj] = v;
    }
  }
}

// ---------------- f64 GEMM: C = alpha*A*B + c1*E1 + dval*I (64x64 tile) ----------------
#define DBM 64
#define DBK 8
__global__ __launch_bounds__(256)
void k_dgemm(const double* __restrict__ A, int lda,
             const double* __restrict__ B, int ldb,
             double* C, int ldc, int K, double alpha,
             const double* E1, int ld1, double c1, double dval)
{
  __shared__ double As[DBK][DBM];
  __shared__ double Bs[DBK][DBM];
  const int tid = threadIdx.x;
  const int tx = tid & 15, ty = tid >> 4;
  const int brow = blockIdx.y * DBM, bcol = blockIdx.x * DBM;

  const int arow = tid >> 2, ac0 = (tid & 3) * 2;   // A tile 64x8
  const int brw  = tid >> 5, bc0 = (tid & 31) * 2;  // B tile 8x64

  const double* Aptr = A + (size_t)(brow + arow) * lda + ac0;
  const double* Bptr = B + (size_t)brw * ldb + (bcol + bc0);

  double2 aPre = *(const double2*)Aptr;
  double2 bPre = *(const double2*)Bptr;

  double acc[4][4];
#pragma unroll
  for (int i = 0; i < 4; ++i)
#pragma unroll
    for (int j = 0; j < 4; ++j) acc[i][j] = 0.0;

  const int nk = K / DBK;
  for (int kt = 0; kt < nk; ++kt) {
    As[ac0 + 0][arow] = aPre.x;
    As[ac0 + 1][arow] = aPre.y;
    Bs[brw][bc0 + 0] = bPre.x;
    Bs[brw][bc0 + 1] = bPre.y;
    __syncthreads();
    if (kt + 1 < nk) {
      aPre = *(const double2*)(Aptr + (size_t)(kt + 1) * DBK);
      bPre = *(const double2*)(Bptr + (size_t)(kt + 1) * DBK * ldb);
    }
#pragma unroll
    for (int kk = 0; kk < DBK; ++kk) {
      double a[4], b[4];
#pragma unroll
      for (int i = 0; i < 4; ++i) a[i] = As[kk][ty * 4 + i];
#pragma unroll
      for (int j = 0; j < 4; ++j) b[j] = Bs[kk][tx * 4 + j];
#pragma unroll
      for (int i = 0; i < 4; ++i)
#pragma unroll
        for (int j = 0; j < 4; ++j)
          acc[i][j] = fma(a[i], b[j], acc[i][j]);
    }
    __syncthreads();
  }
#pragma unroll
  for (int i = 0; i < 4; ++i) {
    const int gi = brow + ty * 4 + i;
#pragma unroll
    for (int j = 0; j < 4; ++j) {
      const int gj = bcol + tx * 4 + j;
      double v = alpha * acc[i][j];
      if (E1) v = fma(c1, E1[(size_t)gi * ld1 + gj], v);
      if (gi == gj) v += dval;
      C[(size_t)gi * ldc + gj] = v;
    }
  }
}

// ---------------- transpose 2048x2048 f32 ----------------
__global__ __launch_bounds__(256)
void k_transpose(const float* __restrict__ in, float* __restrict__ out)
{
  __shared__ float t[32][33];
  const int bx = blockIdx.x * 32, by = blockIdx.y * 32;
  const int lx = threadIdx.x, ly = threadIdx.y; // (32,8)
  for (int dy = 0; dy < 32; dy += 8)
    t[ly + dy][lx] = in[(size_t)(by + ly + dy) * DIMN + bx + lx];
  __syncthreads();
  for (int dy = 0; dy < 32; dy += 8)
    out[(size_t)(bx + ly + dy) * DIMN + by + lx] = t[lx][ly + dy];
}

// ---------------- base case: invert 64x64 f64 (augmented GJ, partial pivoting) ----------------
__global__ __launch_bounds__(512)
void k_gj64(const double* __restrict__ M, int ldm, double* __restrict__ W, int ldw)
{
  __shared__ double a[64][130]; // [A | I], padded
  __shared__ double colp[64];
  __shared__ int s_piv;
  const int tid = threadIdx.x;
  for (int idx = tid; idx < 64 * 64; idx += 512) {
    const int r = idx >> 6, c = idx & 63;
    a[r][c] = M[(size_t)r * ldm + c];
    a[r][64 + c] = (r == c) ? 1.0 : 0.0;
  }
  __syncthreads();
  for (int p = 0; p < 64; ++p) {
    if (tid < 64) { // wave 0: argmax |a[i][p]|, i>=p
      double v = (tid >= p) ? fabs(a[tid][p]) : -1.0;
      int bi = tid;
      for (int off = 32; off; off >>= 1) {
        const double ov = __shfl_down(v, off);
        const int oi = __shfl_down(bi, off);
        if (ov > v) { v = ov; bi = oi; }
      }
      if (tid == 0) s_piv = bi;
    }
    __syncthreads();
    const int piv = s_piv;
    if (piv != p && tid < 128) {
      const double tmp = a[p][tid]; a[p][tid] = a[piv][tid]; a[piv][tid] = tmp;
    }
    __syncthreads();
    const double rpv = 1.0 / a[p][p];
    __syncthreads();
    if (tid < 128) a[p][tid] *= rpv;
    __syncthreads();
    if (tid < 64) colp[tid] = a[tid][p];
    __syncthreads();
    {
      const int c = tid & 127;
      const int g = tid >> 7; // 4 row groups of 16
      const double pc = a[p][c];
      for (int i = g * 16; i < g * 16 + 16; ++i) {
        if (i == p) continue;
        a[i][c] = (c == p) ? 0.0 : fma(-colp[i], pc, a[i][c]);
      }
    }
    __syncthreads();
  }
  for (int idx = tid; idx < 64 * 64; idx += 512) {
    const int r = idx >> 6, c = idx & 63;
    W[(size_t)r * ldw + c] = a[r][64 + c];
  }
}

// ---------------- matvec f32 matrix, f64 vectors: vout = alpha*(Mat*vin) + vadd ----------------
__global__ __launch_bounds__(256)
void k_mv(const float* __restrict__ Mat, const double* __restrict__ vin,
          double* vout, const double* vadd, double alpha)
{
  const int lane = threadIdx.x & 63;
  const int row = blockIdx.x * 4 + (threadIdx.x >> 6);
  const float* mrow = Mat + (size_t)row * DIMN;
  double acc = 0.0;
  for (int p = 0; p < DIMN; p += 256) {
    const float4 m = *(const float4*)&mrow[p + lane * 4];
    const double* vp = &vin[p + lane * 4];
    acc += (double)m.x * vp[0] + (double)m.y * vp[1] + (double)m.z * vp[2] + (double)m.w * vp[3];
  }
  for (int off = 32; off; off >>= 1) acc += __shfl_down(acc, off);
  if (lane == 0) vout[row] = alpha * acc + (vadd ? vadd[row] : 0.0);
}

// ---------------- matvec f64 matrix: vout = alpha*(W*vin) + vadd ----------------
__global__ __launch_bounds__(256)
void k_mv64(const double* __restrict__ W, const double* __restrict__ vin,
            double* vout, const double* vadd, double alpha)
{
  const int lane = threadIdx.x & 63;
  const int row = blockIdx.x * 4 + (threadIdx.x >> 6);
  const double* mrow = W + (size_t)row * DIMN;
  double acc = 0.0;
  for (int p = 0; p < DIMN; p += 256) {
    const int idx = p + lane * 4;
    const double2 m0 = *(const double2*)&mrow[idx];
    const double2 m1 = *(const double2*)&mrow[idx + 2];
    acc += m0.x * vin[idx] + m0.y * vin[idx + 1] + m1.x * vin[idx + 2] + m1.y * vin[idx + 3];
  }
  for (int off = 32; off; off >>= 1) acc += __shfl_down(acc, off);
  if (lane == 0) vout[row] = alpha * acc + (vadd ? vadd[row] : 0.0);
}

// ---------------- residual: r = y - (A*x + 1e-3*x), A f32, vectors f64 ----------------
__global__ __launch_bounds__(256)
void k_mvres(const float* __restrict__ A, const double* __restrict__ x,
             const double* __restrict__ y, double* r)
{
  const int lane = threadIdx.x & 63;
  const int row = blockIdx.x * 4 + (threadIdx.x >> 6);
  const float* mrow = A + (size_t)row * DIMN;
  double acc = 0.0;
  for (int p = 0; p < DIMN; p += 256) {
    const float4 m = *(const float4*)&mrow[p + lane * 4];
    const double* vp = &x[p + lane * 4];
    acc += (double)m.x * vp[0] + (double)m.y * vp[1] + (double)m.z * vp[2] + (double)m.w * vp[3];
  }
  for (int off = 32; off; off >>= 1) acc += __shfl_down(acc, off);
  if (lane == 0) r[row] = y[row] - acc - 1e-3 * x[row];
}

// ---------------- one chain step ----------------
__global__ __launch_bounds__(256)
void k_chain(const float* __restrict__ E, const float* __restrict__ vin, float* __restrict__ vout,
             const float* __restrict__ ERT, const float* __restrict__ uin, float* __restrict__ uout,
             int do_u)
{
  const int lane = threadIdx.x & 63;
  const int w = threadIdx.x >> 6;
  const int b = blockIdx.x;
  const float* mrow; const float* xin; float* xout; int row;
  if (b < 512) { row = b * 4 + w; mrow = E + (size_t)row * DIMN; xin = vin; xout = vout; }
  else { if (!do_u) return; row = (b - 512) * 4 + w; mrow = ERT + (size_t)row * DIMN; xin = uin; xout = uout; }
  float acc = 0.f;
  for (int p = 0; p < DIMN; p += 256) {
    const float4 m = *(const float4*)&mrow[p + lane * 4];
    const float* vp = &xin[p + lane * 4];
    acc = fmaf(m.x, vp[0], acc);
    acc = fmaf(m.y, vp[1], acc);
    acc = fmaf(m.z, vp[2], acc);
    acc = fmaf(m.w, vp[3], acc);
  }
  for (int off = 32; off; off >>= 1) acc += __shfl_down(acc, off);
  if (lane == 0) xout[row] = xin[row] + acc;
}

// ---------------- terms: out[8191-(128j+i)] = dot(U[j], V[i]) ----------------
__global__ __launch_bounds__(256)
void k_terms(const float* __restrict__ U, const float* __restrict__ V, float* __restrict__ out)
{
  const int lane = threadIdx.x & 63;
  const int t = blockIdx.x * 4 + (threadIdx.x >> 6);
  const int j = t >> 7, i = t & 127;
  const float* u = U + (size_t)j * DIMN;
  const float* v = V + (size_t)i * DIMN;
  float acc = 0.f;
  for (int p = 0; p < DIMN; p += 256) {
    const float4 a4 = *(const float4*)&u[p + lane * 4];
    const float4 b4 = *(const float4*)&v[p + lane * 4];
    acc = fmaf(a4.x, b4.x, acc); acc = fmaf(a4.y, b4.y, acc);
    acc = fmaf(a4.z, b4.z, acc); acc = fmaf(a4.w, b4.w, acc);
  }
  for (int off = 32; off; off >>= 1) acc += __shfl_down(acc, off);
  if (lane == 0) out[MSTEPS - 1 - t] = acc;
}

// ---------------- small vector inits ----------------
__global__ void k_vecinit(const float* __restrict__ B, double* __restrict__ b64,
                          const float* __restrict__ Cv, float* __restrict__ U0)
{
  const int i = blockIdx.x * 256 + threadIdx.x;
  if (i < DIMN) { b64[i] = 0.01 * (double)B[i]; U0[i] = Cv[i]; }
}
__global__ void k_v0(const double* __restrict__ x64, float* __restrict__ V0)
{
  const int i = blockIdx.x * 256 + threadIdx.x;
  if (i < DIMN) V0[i] = (float)x64[i];
}

// ---------------- host helpers ----------------
static inline void gemm(hipStream_t s, const float* A, int lda, const float* B, int ldb,
                        float* C, int ldc, int m, int n, int k, float alpha,
                        const float* E1 = nullptr, int ld1 = 0, float c1 = 0.f,
                        const float* E2 = nullptr, int ld2 = 0, float c2 = 0.f,
                        const float* E3 = nullptr, int ld3 = 0, float c3 = 0.f,
                        float dval = 0.f)
{
  dim3 grid(n / GBN, m / GBM), block(256);
  k_gemm<<<grid, block, 0, s>>>(A, lda, B, ldb, C, ldc, k, alpha,
                                E1, ld1, c1, E2, ld2, c2, E3, ld3, c3, dval);
}

static inline void dgemm(hipStream_t s, const double* A, int lda, const double* B, int ldb,
                         double* C, int ldc, int n, double alpha,
                         const double* E1 = nullptr, int ld1 = 0, double c1 = 0.0)
{
  dim3 grid(n / DBM, n / DBM), block(256);
  k_dgemm<<<grid, block, 0, s>>>(A, lda, B, ldb, C, ldc, n, alpha, E1, ld1, c1, 0.0);
}

// f64 block-Schur inversion. Destroys M (S over M22, U over M21). scr holds T (h^2/level).
static void invert_rec64(hipStream_t s, double* M, int ldm, double* W, int ldw, int n, double* scr)
{
  if (n == 64) { k_gj64<<<dim3(1), dim3(512), 0, s>>>(M, ldm, W, ldw); return; }
  const int h = n / 2;
  double* T = scr;
  double* deeper = scr + (size_t)h * h;
  double* M12 = M + h;
  double* M21 = M + (size_t)h * ldm;
  double* M22 = M + (size_t)h * ldm + h;
  double* W11 = W;
  double* W12 = W + h;
  double* W21 = W + (size_t)h * ldw;
  double* W22 = W + (size_t)h * ldw + h;
  invert_rec64(s, M, ldm, W11, ldw, h, deeper);
  dgemm(s, M21, ldm, W11, ldw, T, h, h, 1.0);                      // T = M21*W11
  dgemm(s, T, h, M12, ldm, M22, ldm, h, -1.0, M22, ldm, 1.0);      // S = M22 - T*M12 (in place)
  invert_rec64(s, M22, ldm, W22, ldw, h, deeper);                  // W22 = inv(S)
  dgemm(s, W11, ldw, M12, ldm, M21, ldm, h, 1.0);                  // U = W11*M12 (over dead M21)
  dgemm(s, M21, ldm, W22, ldw, W12, ldw, h, -1.0);                 // W12 = -U*W22
  dgemm(s, W22, ldw, T, h, W21, ldw, h, -1.0);                     // W21 = -W22*T
  dgemm(s, W12, ldw, T, h, W11, ldw, h, -1.0, W11, ldw, 1.0);      // W11 -= W12*T
}

extern "C" void kernel_launch(void* const* d_in, const int* in_sizes, int n_in,
                              void* d_out, int out_size, void* d_ws, size_t ws_size,
                              hipStream_t stream)
{
  const float* dA = (const float*)d_in[0];
  const float* dB = (const float*)d_in[1];
  const float* dC = (const float*)d_in[2];
  float* out = (float*)d_out;

  // Arena layout (floats): Ebuf | t1 | t2 | t3 | t4 | scr64(2*SCRD) | vecs
  float* fb = (float*)d_ws;
  float* Ebuf = fb;                 // E = exp(0.01A) - I            (f32, persistent)
  float* t1 = fb + NN;              // Y2      | M64 low half
  float* t2 = t1 + NN;              // Y3      | M64 high half
  float* t3 = t2 + NN;              // Hi/ERT  | W64 low half
  float* t4 = t3 + NN;              // ER      | W64 high half
  double* M64 = (double*)t1;        // spans t1,t2 (32MB)
  double* W64 = (double*)t3;        // spans t3,t4 (32MB)
  double* scr64 = (double*)(fb + 5 * NN);
  double* y64 = scr64 + SCRD;
  double* x64 = y64 + DIMN;
  double* r64 = x64 + DIMN;
  double* b64 = r64 + DIMN;
  float* V  = (float*)(b64 + DIMN);            // 128 x 2048
  float* Uc = V + (size_t)RBLK * DIMN;         // 64 x 2048

  const size_t needed = (5 * NN + 2 * SCRD) * 4 + 4 * (size_t)DIMN * 8
                        + (size_t)(RBLK + NJROWS) * DIMN * 4;
  if (ws_size < needed) return; // clean zero-output failure instead of OOB

  const float* NUL = nullptr;
  dim3 cb(256), cg(2048);

  // ---- Phase 1: W64 = inv(A + 1e-3 I) in f64 (destroys M64) ----
  k_fill64<<<cg, cb, 0, stream>>>(dA, M64);
  invert_rec64(stream, M64, DIMN, W64, DIMN, DIMN, scr64);

  // ---- Phase 2: E = exp(0.01A) - I, deg-3 Horner: X*(I + (X/2)(I + X/3)), X=0.01A ----
  k_combine4<<<cg, cb, 0, stream>>>(t1, dA, 0.01f / 3.f, NUL, 0, NUL, 0, NUL, 0, 1.f);
  gemm(stream, dA, DIMN, t1, DIMN, t2, DIMN, DIMN, DIMN, DIMN, 0.005f,
       NUL, 0, 0, NUL, 0, 0, NUL, 0, 0, 1.f);                                  // t2 = I + (X/2)t1
  gemm(stream, dA, DIMN, t2, DIMN, Ebuf, DIMN, DIMN, DIMN, DIMN, 0.01f);       // E = X*t2

  // ---- Phase 3: Bbar via y = E*(0.01B); x = W*y; 6x f64 iterative refinement ----
  k_vecinit<<<dim3(8), cb, 0, stream>>>(dB, b64, dC, Uc);                      // b64=0.01B, U[0]=C
  k_mv<<<dim3(512), cb, 0, stream>>>(Ebuf, b64, y64, (const double*)nullptr, 1.0);
  k_mv64<<<dim3(512), cb, 0, stream>>>(W64, y64, x64, (const double*)nullptr, 1.0);
  for (int it = 0; it < 6; ++it) {
    k_mvres<<<dim3(512), cb, 0, stream>>>(dA, x64, y64, r64);                  // r = y - (A+1e-3I)x
    k_mv64<<<dim3(512), cb, 0, stream>>>(W64, r64, x64, x64, 1.0);             // x += W*r
  }
  k_v0<<<dim3(8), cb, 0, stream>>>(x64, V);                                    // V[0] = Bbar

  // ---- Phase 4: ER = exp(1.28A) - I, deg-6 PS (W64 dead now) ----
  // Y=1.28A: Y2 -> t1, Y3 -> t2, Hi = I/6 + Y/24 + Y2/120 + Y3/720 -> t3
  gemm(stream, dA, DIMN, dA, DIMN, t1, DIMN, DIMN, DIMN, DIMN, 1.6384f);       // Y2
  gemm(stream, dA, DIMN, t1, DIMN, t2, DIMN, DIMN, DIMN, DIMN, 1.28f);         // Y3
  k_combine4<<<cg, cb, 0, stream>>>(t3, dA, 1.28f / 24.f, t1, 1.f / 120.f,
                                    t2, 1.f / 720.f, NUL, 0, 1.f / 6.f);       // Hi
  gemm(stream, t2, DIMN, t3, DIMN, t4, DIMN, DIMN, DIMN, DIMN, 1.f,
       t1, DIMN, 0.5f, dA, DIMN, 1.28f);                                       // ER = Y3*Hi + Y2/2 + Y
  k_transpose<<<dim3(64, 64), dim3(32, 8), 0, stream>>>(t4, t3);               // ERT -> t3

  // ---- Phase 5: serial chains + terms ----
  for (int s = 0; s < RBLK - 1; ++s) {
    const int du = (s < NJROWS - 1) ? 1 : 0;
    k_chain<<<dim3(1024), cb, 0, stream>>>(Ebuf, V + (size_t)s * DIMN, V + (size_t)(s + 1) * DIMN,
                                           t3, Uc + (size_t)s * DIMN, Uc + (size_t)(s + 1) * DIMN, du);
  }
  k_terms<<<dim3(2048), cb, 0, stream>>>(Uc, V, out);
}

// Round 4
// 8286.221 us; speedup vs baseline: 1.0717x; 1.0717x over previous
//
#include <hip/hip_runtime.h>

// ZOH linear layer: K[1,8192], dim 2048.
// E=expm(.01A)-I (deg-2, 1 f32 GEMM); ER=expm(1.28A)-I (deg-4 PS, 2 f32 GEMMs);
// W=inv(A+1e-3 I) in f64: block-Schur recursion (VALU f64 GEMM, known-good) + pivoted
// f64 GJ 64x64 base + f64 iterative refinement (vector only, 6 iters).
// K[128j+i] = (C*AR^j)·(A^i*Bbar): two serial matvec chains (127 steps) + dots.
// Arena ~96.7MB: Ebuf | t1 t2 (=M64) | t3 t4 (=W64) | scr64 | vectors.

#define DIMN 2048
#define MSTEPS 8192
#define RBLK 128
#define NJROWS 64
#define NN ((size_t)DIMN * DIMN)
// nested Schur scratch: sum h^2 for h = 1024,512,256,128,64 (doubles)
#define SCRD ((size_t)(1024*1024 + 512*512 + 256*256 + 128*128 + 64*64))

// ---------------- elementwise f32: out = c1*i1+c2*i2+c3*i3+c4*i4 + dval*I ----------------
__global__ __launch_bounds__(256)
void k_combine4(float* out,
                const float* i1, float c1, const float* i2, float c2,
                const float* i3, float c3, const float* i4, float c4,
                float dval)
{
  const int total = DIMN * DIMN;
  for (int idx = blockIdx.x * 256 + threadIdx.x; idx < total; idx += gridDim.x * 256) {
    float v = 0.f;
    if (i1) v = fmaf(c1, i1[idx], v);
    if (i2) v = fmaf(c2, i2[idx], v);
    if (i3) v = fmaf(c3, i3[idx], v);
    if (i4) v = fmaf(c4, i4[idx], v);
    if ((idx >> 11) == (idx & 2047)) v += dval;
    out[idx] = v;
  }
}

// ---------------- M64 = (double)A + 1e-3 I ----------------
__global__ __launch_bounds__(256)
void k_fill64(const float* __restrict__ A, double* __restrict__ M)
{
  const int total = DIMN * DIMN;
  for (int idx = blockIdx.x * 256 + threadIdx.x; idx < total; idx += gridDim.x * 256) {
    double v = (double)A[idx];
    if ((idx >> 11) == (idx & 2047)) v += 1e-3;
    M[idx] = v;
  }
}

// ---------------- f32 GEMM: C = alpha*A*B + c1*E1 + c2*E2 + c3*E3 + dval*I ----------------
#define GBM 128
#define GBN 128
#define GBK 8
__global__ __launch_bounds__(256)
void k_gemm(const float* __restrict__ A, int lda,
            const float* __restrict__ B, int ldb,
            float* C, int ldc, int K, float alpha,
            const float* E1, int ld1, float c1,
            const float* E2, int ld2, float c2,
            const float* E3, int ld3, float c3,
            float dval)
{
  __shared__ float As[GBK][GBM];
  __shared__ float Bs[GBK][GBN];
  const int tid = threadIdx.x;
  const int tx = tid & 15, ty = tid >> 4;
  const int brow = blockIdx.y * GBM, bcol = blockIdx.x * GBN;

  const int arow = tid >> 1, ac0 = (tid & 1) * 4;   // A tile 128x8
  const int brw  = tid >> 5, bc0 = (tid & 31) * 4;  // B tile 8x128

  const float* Aptr = A + (size_t)(brow + arow) * lda + ac0;
  const float* Bptr = B + (size_t)brw * ldb + (bcol + bc0);

  float4 aPre = *(const float4*)Aptr;
  float4 bPre = *(const float4*)Bptr;

  float acc[8][8];
#pragma unroll
  for (int i = 0; i < 8; ++i)
#pragma unroll
    for (int j = 0; j < 8; ++j) acc[i][j] = 0.f;

  const int nk = K / GBK;
  for (int kt = 0; kt < nk; ++kt) {
    As[ac0 + 0][arow] = aPre.x;
    As[ac0 + 1][arow] = aPre.y;
    As[ac0 + 2][arow] = aPre.z;
    As[ac0 + 3][arow] = aPre.w;
    *(float4*)&Bs[brw][bc0] = bPre;
    __syncthreads();
    if (kt + 1 < nk) {
      aPre = *(const float4*)(Aptr + (size_t)(kt + 1) * GBK);
      bPre = *(const float4*)(Bptr + (size_t)(kt + 1) * GBK * ldb);
    }
#pragma unroll
    for (int kk = 0; kk < GBK; ++kk) {
      float a[8], b[8];
      *(float4*)&a[0] = *(const float4*)&As[kk][ty * 8];
      *(float4*)&a[4] = *(const float4*)&As[kk][ty * 8 + 4];
      *(float4*)&b[0] = *(const float4*)&Bs[kk][tx * 8];
      *(float4*)&b[4] = *(const float4*)&Bs[kk][tx * 8 + 4];
#pragma unroll
      for (int i = 0; i < 8; ++i)
#pragma unroll
        for (int j = 0; j < 8; ++j)
          acc[i][j] = fmaf(a[i], b[j], acc[i][j]);
    }
    __syncthreads();
  }
#pragma unroll
  for (int i = 0; i < 8; ++i) {
    const int gi = brow + ty * 8 + i;
#pragma unroll
    for (int j = 0; j < 8; ++j) {
      const int gj = bcol + tx * 8 + j;
      float v = alpha * acc[i][j];
      if (E1) v = fmaf(c1, E1[(size_t)gi * ld1 + gj], v);
      if (E2) v = fmaf(c2, E2[(size_t)gi * ld2 + gj], v);
      if (E3) v = fmaf(c3, E3[(size_t)gi * ld3 + gj], v);
      if (gi == gj) v += dval;
      C[(size_t)gi * ldc + gj] = v;
    }
  }
}

// ---------------- f64 GEMM (VALU, known-good): C = alpha*A*B + c1*E1 (64x64 tile) ----------------
#define DBM 64
#define DBK 8
__global__ __launch_bounds__(256)
void k_dgemm(const double* __restrict__ A, int lda,
             const double* __restrict__ B, int ldb,
             double* C, int ldc, int K, double alpha,
             const double* E1, int ld1, double c1, double dval)
{
  __shared__ double As[DBK][DBM];
  __shared__ double Bs[DBK][DBM];
  const int tid = threadIdx.x;
  const int tx = tid & 15, ty = tid >> 4;
  const int brow = blockIdx.y * DBM, bcol = blockIdx.x * DBM;

  const int arow = tid >> 2, ac0 = (tid & 3) * 2;   // A tile 64x8
  const int brw  = tid >> 5, bc0 = (tid & 31) * 2;  // B tile 8x64

  const double* Aptr = A + (size_t)(brow + arow) * lda + ac0;
  const double* Bptr = B + (size_t)brw * ldb + (bcol + bc0);

  double2 aPre = *(const double2*)Aptr;
  double2 bPre = *(const double2*)Bptr;

  double acc[4][4];
#pragma unroll
  for (int i = 0; i < 4; ++i)
#pragma unroll
    for (int j = 0; j < 4; ++j) acc[i][j] = 0.0;

  const int nk = K / DBK;
  for (int kt = 0; kt < nk; ++kt) {
    As[ac0 + 0][arow] = aPre.x;
    As[ac0 + 1][arow] = aPre.y;
    Bs[brw][bc0 + 0] = bPre.x;
    Bs[brw][bc0 + 1] = bPre.y;
    __syncthreads();
    if (kt + 1 < nk) {
      aPre = *(const double2*)(Aptr + (size_t)(kt + 1) * DBK);
      bPre = *(const double2*)(Bptr + (size_t)(kt + 1) * DBK * ldb);
    }
#pragma unroll
    for (int kk = 0; kk < DBK; ++kk) {
      double a[4], b[4];
#pragma unroll
      for (int i = 0; i < 4; ++i) a[i] = As[kk][ty * 4 + i];
#pragma unroll
      for (int j = 0; j < 4; ++j) b[j] = Bs[kk][tx * 4 + j];
#pragma unroll
      for (int i = 0; i < 4; ++i)
#pragma unroll
        for (int j = 0; j < 4; ++j)
          acc[i][j] = fma(a[i], b[j], acc[i][j]);
    }
    __syncthreads();
  }
#pragma unroll
  for (int i = 0; i < 4; ++i) {
    const int gi = brow + ty * 4 + i;
#pragma unroll
    for (int j = 0; j < 4; ++j) {
      const int gj = bcol + tx * 4 + j;
      double v = alpha * acc[i][j];
      if (E1) v = fma(c1, E1[(size_t)gi * ld1 + gj], v);
      if (gi == gj) v += dval;
      C[(size_t)gi * ldc + gj] = v;
    }
  }
}

// ---------------- transpose 2048x2048 f32 ----------------
__global__ __launch_bounds__(256)
void k_transpose(const float* __restrict__ in, float* __restrict__ out)
{
  __shared__ float t[32][33];
  const int bx = blockIdx.x * 32, by = blockIdx.y * 32;
  const int lx = threadIdx.x, ly = threadIdx.y; // (32,8)
  for (int dy = 0; dy < 32; dy += 8)
    t[ly + dy][lx] = in[(size_t)(by + ly + dy) * DIMN + bx + lx];
  __syncthreads();
  for (int dy = 0; dy < 32; dy += 8)
    out[(size_t)(bx + ly + dy) * DIMN + by + lx] = t[lx][ly + dy];
}

// ---------------- base case: invert 64x64 f64 (augmented GJ, partial pivoting) ----------------
__global__ __launch_bounds__(512)
void k_gj64(const double* __restrict__ M, int ldm, double* __restrict__ W, int ldw)
{
  __shared__ double a[64][130]; // [A | I], padded
  __shared__ double colp[64];
  __shared__ int s_piv;
  const int tid = threadIdx.x;
  for (int idx = tid; idx < 64 * 64; idx += 512) {
    const int r = idx >> 6, c = idx & 63;
    a[r][c] = M[(size_t)r * ldm + c];
    a[r][64 + c] = (r == c) ? 1.0 : 0.0;
  }
  __syncthreads();
  for (int p = 0; p < 64; ++p) {
    if (tid < 64) { // wave 0: argmax |a[i][p]|, i>=p
      double v = (tid >= p) ? fabs(a[tid][p]) : -1.0;
      int bi = tid;
      for (int off = 32; off; off >>= 1) {
        const double ov = __shfl_down(v, off);
        const int oi = __shfl_down(bi, off);
        if (ov > v) { v = ov; bi = oi; }
      }
      if (tid == 0) s_piv = bi;
    }
    __syncthreads();
    const int piv = s_piv;
    if (piv != p && tid < 128) {
      const double tmp = a[p][tid]; a[p][tid] = a[piv][tid]; a[piv][tid] = tmp;
    }
    __syncthreads();
    const double rpv = 1.0 / a[p][p];
    __syncthreads();
    if (tid < 128) a[p][tid] *= rpv;
    __syncthreads();
    if (tid < 64) colp[tid] = a[tid][p];
    __syncthreads();
    {
      const int c = tid & 127;
      const int g = tid >> 7; // 4 row groups of 16
      const double pc = a[p][c];
      for (int i = g * 16; i < g * 16 + 16; ++i) {
        if (i == p) continue;
        a[i][c] = (c == p) ? 0.0 : fma(-colp[i], pc, a[i][c]);
      }
    }
    __syncthreads();
  }
  for (int idx = tid; idx < 64 * 64; idx += 512) {
    const int r = idx >> 6, c = idx & 63;
    W[(size_t)r * ldw + c] = a[r][64 + c];
  }
}

// ---------------- matvec f32 matrix, f64 vectors: vout = alpha*(Mat*vin) + vadd ----------------
__global__ __launch_bounds__(256)
void k_mv(const float* __restrict__ Mat, const double* __restrict__ vin,
          double* vout, const double* vadd, double alpha)
{
  const int lane = threadIdx.x & 63;
  const int row = blockIdx.x * 4 + (threadIdx.x >> 6);
  const float* mrow = Mat + (size_t)row * DIMN;
  double acc = 0.0;
  for (int p = 0; p < DIMN; p += 256) {
    const float4 m = *(const float4*)&mrow[p + lane * 4];
    const double* vp = &vin[p + lane * 4];
    acc += (double)m.x * vp[0] + (double)m.y * vp[1] + (double)m.z * vp[2] + (double)m.w * vp[3];
  }
  for (int off = 32; off; off >>= 1) acc += __shfl_down(acc, off);
  if (lane == 0) vout[row] = alpha * acc + (vadd ? vadd[row] : 0.0);
}

// ---------------- matvec f64 matrix: vout = alpha*(W*vin) + vadd ----------------
__global__ __launch_bounds__(256)
void k_mv64(const double* __restrict__ W, const double* __restrict__ vin,
            double* vout, const double* vadd, double alpha)
{
  const int lane = threadIdx.x & 63;
  const int row = blockIdx.x * 4 + (threadIdx.x >> 6);
  const double* mrow = W + (size_t)row * DIMN;
  double acc = 0.0;
  for (int p = 0; p < DIMN; p += 256) {
    const int idx = p + lane * 4;
    const double2 m0 = *(const double2*)&mrow[idx];
    const double2 m1 = *(const double2*)&mrow[idx + 2];
    acc += m0.x * vin[idx] + m0.y * vin[idx + 1] + m1.x * vin[idx + 2] + m1.y * vin[idx + 3];
  }
  for (int off = 32; off; off >>= 1) acc += __shfl_down(acc, off);
  if (lane == 0) vout[row] = alpha * acc + (vadd ? vadd[row] : 0.0);
}

// ---------------- residual: r = y - (A*x + 1e-3*x), A f32, vectors f64 ----------------
__global__ __launch_bounds__(256)
void k_mvres(const float* __restrict__ A, const double* __restrict__ x,
             const double* __restrict__ y, double* r)
{
  const int lane = threadIdx.x & 63;
  const int row = blockIdx.x * 4 + (threadIdx.x >> 6);
  const float* mrow = A + (size_t)row * DIMN;
  double acc = 0.0;
  for (int p = 0; p < DIMN; p += 256) {
    const float4 m = *(const float4*)&mrow[p + lane * 4];
    const double* vp = &x[p + lane * 4];
    acc += (double)m.x * vp[0] + (double)m.y * vp[1] + (double)m.z * vp[2] + (double)m.w * vp[3];
  }
  for (int off = 32; off; off >>= 1) acc += __shfl_down(acc, off);
  if (lane == 0) r[row] = y[row] - acc - 1e-3 * x[row];
}

// ---------------- one chain step ----------------
__global__ __launch_bounds__(256)
void k_chain(const float* __restrict__ E, const float* __restrict__ vin, float* __restrict__ vout,
             const float* __restrict__ ERT, const float* __restrict__ uin, float* __restrict__ uout,
             int do_u)
{
  const int lane = threadIdx.x & 63;
  const int w = threadIdx.x >> 6;
  const int b = blockIdx.x;
  const float* mrow; const float* xin; float* xout; int row;
  if (b < 512) { row = b * 4 + w; mrow = E + (size_t)row * DIMN; xin = vin; xout = vout; }
  else { if (!do_u) return; row = (b - 512) * 4 + w; mrow = ERT + (size_t)row * DIMN; xin = uin; xout = uout; }
  float acc = 0.f;
  for (int p = 0; p < DIMN; p += 256) {
    const float4 m = *(const float4*)&mrow[p + lane * 4];
    const float* vp = &xin[p + lane * 4];
    acc = fmaf(m.x, vp[0], acc);
    acc = fmaf(m.y, vp[1], acc);
    acc = fmaf(m.z, vp[2], acc);
    acc = fmaf(m.w, vp[3], acc);
  }
  for (int off = 32; off; off >>= 1) acc += __shfl_down(acc, off);
  if (lane == 0) xout[row] = xin[row] + acc;
}

// ---------------- terms: out[8191-(128j+i)] = dot(U[j], V[i]) ----------------
__global__ __launch_bounds__(256)
void k_terms(const float* __restrict__ U, const float* __restrict__ V, float* __restrict__ out)
{
  const int lane = threadIdx.x & 63;
  const int t = blockIdx.x * 4 + (threadIdx.x >> 6);
  const int j = t >> 7, i = t & 127;
  const float* u = U + (size_t)j * DIMN;
  const float* v = V + (size_t)i * DIMN;
  float acc = 0.f;
  for (int p = 0; p < DIMN; p += 256) {
    const float4 a4 = *(const float4*)&u[p + lane * 4];
    const float4 b4 = *(const float4*)&v[p + lane * 4];
    acc = fmaf(a4.x, b4.x, acc); acc = fmaf(a4.y, b4.y, acc);
    acc = fmaf(a4.z, b4.z, acc); acc = fmaf(a4.w, b4.w, acc);
  }
  for (int off = 32; off; off >>= 1) acc += __shfl_down(acc, off);
  if (lane == 0) out[MSTEPS - 1 - t] = acc;
}

// ---------------- small vector inits ----------------
__global__ void k_vecinit(const float* __restrict__ B, double* __restrict__ b64,
                          const float* __restrict__ Cv, float* __restrict__ U0)
{
  const int i = blockIdx.x * 256 + threadIdx.x;
  if (i < DIMN) { b64[i] = 0.01 * (double)B[i]; U0[i] = Cv[i]; }
}
__global__ void k_v0(const double* __restrict__ x64, float* __restrict__ V0)
{
  const int i = blockIdx.x * 256 + threadIdx.x;
  if (i < DIMN) V0[i] = (float)x64[i];
}

// ---------------- host helpers ----------------
static inline void gemm(hipStream_t s, const float* A, int lda, const float* B, int ldb,
                        float* C, int ldc, int m, int n, int k, float alpha,
                        const float* E1 = nullptr, int ld1 = 0, float c1 = 0.f,
                        const float* E2 = nullptr, int ld2 = 0, float c2 = 0.f,
                        const float* E3 = nullptr, int ld3 = 0, float c3 = 0.f,
                        float dval = 0.f)
{
  dim3 grid(n / GBN, m / GBM), block(256);
  k_gemm<<<grid, block, 0, s>>>(A, lda, B, ldb, C, ldc, k, alpha,
                                E1, ld1, c1, E2, ld2, c2, E3, ld3, c3, dval);
}

static inline void dgemm(hipStream_t s, const double* A, int lda, const double* B, int ldb,
                         double* C, int ldc, int n, double alpha,
                         const double* E1 = nullptr, int ld1 = 0, double c1 = 0.0)
{
  dim3 grid(n / DBM, n / DBM), block(256);
  k_dgemm<<<grid, block, 0, s>>>(A, lda, B, ldb, C, ldc, n, alpha, E1, ld1, c1, 0.0);
}

// f64 block-Schur inversion. Destroys M (S over M22, U over M21). scr holds T (h^2/level).
static void invert_rec64(hipStream_t s, double* M, int ldm, double* W, int ldw, int n, double* scr)
{
  if (n == 64) { k_gj64<<<dim3(1), dim3(512), 0, s>>>(M, ldm, W, ldw); return; }
  const int h = n / 2;
  double* T = scr;
  double* deeper = scr + (size_t)h * h;
  double* M12 = M + h;
  double* M21 = M + (size_t)h * ldm;
  double* M22 = M + (size_t)h * ldm + h;
  double* W11 = W;
  double* W12 = W + h;
  double* W21 = W + (size_t)h * ldw;
  double* W22 = W + (size_t)h * ldw + h;
  invert_rec64(s, M, ldm, W11, ldw, h, deeper);
  dgemm(s, M21, ldm, W11, ldw, T, h, h, 1.0);                      // T = M21*W11
  dgemm(s, T, h, M12, ldm, M22, ldm, h, -1.0, M22, ldm, 1.0);      // S = M22 - T*M12 (in place)
  invert_rec64(s, M22, ldm, W22, ldw, h, deeper);                  // W22 = inv(S)
  dgemm(s, W11, ldw, M12, ldm, M21, ldm, h, 1.0);                  // U = W11*M12 (over dead M21)
  dgemm(s, M21, ldm, W22, ldw, W12, ldw, h, -1.0);                 // W12 = -U*W22
  dgemm(s, W22, ldw, T, h, W21, ldw, h, -1.0);                     // W21 = -W22*T
  dgemm(s, W12, ldw, T, h, W11, ldw, h, -1.0, W11, ldw, 1.0);      // W11 -= W12*T
}

extern "C" void kernel_launch(void* const* d_in, const int* in_sizes, int n_in,
                              void* d_out, int out_size, void* d_ws, size_t ws_size,
                              hipStream_t stream)
{
  const float* dA = (const float*)d_in[0];
  const float* dB = (const float*)d_in[1];
  const float* dC = (const float*)d_in[2];
  float* out = (float*)d_out;

  // Arena layout (floats): Ebuf | t1 | t2 | t3 | t4 | scr64(2*SCRD) | vecs
  float* fb = (float*)d_ws;
  float* Ebuf = fb;                 // E = exp(0.01A) - I            (f32, persistent)
  float* t1 = fb + NN;              // Y2      | M64 low half
  float* t2 = t1 + NN;              //         | M64 high half
  float* t3 = t2 + NN;              // H/ERT   | W64 low half
  float* t4 = t3 + NN;              // ER      | W64 high half
  double* M64 = (double*)t1;        // spans t1,t2 (32MB)
  double* W64 = (double*)t3;        // spans t3,t4 (32MB)
  double* scr64 = (double*)(fb + 5 * NN);
  double* y64 = scr64 + SCRD;
  double* x64 = y64 + DIMN;
  double* r64 = x64 + DIMN;
  double* b64 = r64 + DIMN;
  float* V  = (float*)(b64 + DIMN);            // 128 x 2048
  float* Uc = V + (size_t)RBLK * DIMN;         // 64 x 2048

  const size_t needed = (5 * NN + 2 * SCRD) * 4 + 4 * (size_t)DIMN * 8
                        + (size_t)(RBLK + NJROWS) * DIMN * 4;
  if (ws_size < needed) return; // clean zero-output failure instead of OOB

  const float* NUL = nullptr;
  dim3 cb(256), cg(2048);

  // ---- Phase 1: W64 = inv(A + 1e-3 I) in f64 (destroys M64) ----
  k_fill64<<<cg, cb, 0, stream>>>(dA, M64);
  invert_rec64(stream, M64, DIMN, W64, DIMN, DIMN, scr64);

  // ---- Phase 2: E = exp(0.01A) - I, deg-2: E = (1e-4/2)A^2 + 0.01A ----
  // (dropped X^3/6: output-level error ~2e-13 abs, budget 1.7e-7)
  gemm(stream, dA, DIMN, dA, DIMN, Ebuf, DIMN, DIMN, DIMN, DIMN, 5e-5f,
       dA, DIMN, 0.01f);

  // ---- Phase 3: Bbar via y = E*(0.01B); x = W*y; 6x f64 iterative refinement ----
  k_vecinit<<<dim3(8), cb, 0, stream>>>(dB, b64, dC, Uc);                      // b64=0.01B, U[0]=C
  k_mv<<<dim3(512), cb, 0, stream>>>(Ebuf, b64, y64, (const double*)nullptr, 1.0);
  k_mv64<<<dim3(512), cb, 0, stream>>>(W64, y64, x64, (const double*)nullptr, 1.0);
  for (int it = 0; it < 6; ++it) {
    k_mvres<<<dim3(512), cb, 0, stream>>>(dA, x64, y64, r64);                  // r = y - (A+1e-3I)x
    k_mv64<<<dim3(512), cb, 0, stream>>>(W64, r64, x64, x64, 1.0);             // x += W*r
  }
  k_v0<<<dim3(8), cb, 0, stream>>>(x64, V);                                    // V[0] = Bbar

  // ---- Phase 4: ER = exp(1.28A) - I, deg-4 PS (W64 dead now), Y = 1.28A ----
  // Y2 -> t1; H = Y/6 + Y2/24 -> t3; ER = Y2*H + Y2/2 + Y -> t4
  gemm(stream, dA, DIMN, dA, DIMN, t1, DIMN, DIMN, DIMN, DIMN, 1.6384f);       // Y2
  k_combine4<<<cg, cb, 0, stream>>>(t3, dA, 1.28f / 6.f, t1, 1.f / 24.f,
                                    NUL, 0, NUL, 0, 0.f);                      // H
  gemm(stream, t1, DIMN, t3, DIMN, t4, DIMN, DIMN, DIMN, DIMN, 1.f,
       t1, DIMN, 0.5f, dA, DIMN, 1.28f);                                       // ER
  k_transpose<<<dim3(64, 64), dim3(32, 8), 0, stream>>>(t4, t3);               // ERT -> t3

  // ---- Phase 5: serial chains + terms ----
  for (int s = 0; s < RBLK - 1; ++s) {
    const int du = (s < NJROWS - 1) ? 1 : 0;
    k_chain<<<dim3(1024), cb, 0, stream>>>(Ebuf, V + (size_t)s * DIMN, V + (size_t)(s + 1) * DIMN,
                                           t3, Uc + (size_t)s * DIMN, Uc + (size_t)(s + 1) * DIMN, du);
  }
  k_terms<<<dim3(2048), cb, 0, stream>>>(Uc, V, out);
}

// Round 5
// 7571.534 us; speedup vs baseline: 1.1729x; 1.0944x over previous
//
#include <hip/hip_runtime.h>

// ZOH linear layer: K[1,8192], dim 2048.
// E=expm(.01A)-I (deg-2, 1 f32 GEMM); ER=expm(0.91A)-I (deg-4 PS, 2 f32 GEMMs);
// W=inv(A+1e-3 I) in f64: block-Schur recursion (VALU f64 GEMM) + pivoted
// f64 GJ 64x64 base (v2: 3 syncs/iter, perm bookkeeping) + 2x f64 IR (vector).
// K[91j+i] = (C*AR^j)·(A^i*Bbar): two balanced serial matvec chains (90 steps) + dots.
// Arena ~96.2MB: Ebuf | t1 t2 (=M64) | t3 t4 (=W64) | scr64 | vectors.

#define DIMN 2048
#define MSTEPS 8192
#define RSPLIT 91          // sqrt split: t = 91j + i, i,j in [0,91)
#define NSTEPS 90          // serial chain steps for each of V and U
#define NN ((size_t)DIMN * DIMN)
// nested Schur scratch: sum h^2 for h = 1024,512,256,128,64 (doubles)
#define SCRD ((size_t)(1024*1024 + 512*512 + 256*256 + 128*128 + 64*64))

// ---------------- elementwise f32: out = c1*i1+c2*i2+c3*i3+c4*i4 + dval*I ----------------
__global__ __launch_bounds__(256)
void k_combine4(float* out,
                const float* i1, float c1, const float* i2, float c2,
                const float* i3, float c3, const float* i4, float c4,
                float dval)
{
  const int total = DIMN * DIMN;
  for (int idx = blockIdx.x * 256 + threadIdx.x; idx < total; idx += gridDim.x * 256) {
    float v = 0.f;
    if (i1) v = fmaf(c1, i1[idx], v);
    if (i2) v = fmaf(c2, i2[idx], v);
    if (i3) v = fmaf(c3, i3[idx], v);
    if (i4) v = fmaf(c4, i4[idx], v);
    if ((idx >> 11) == (idx & 2047)) v += dval;
    out[idx] = v;
  }
}

// ---------------- M64 = (double)A + 1e-3 I ----------------
__global__ __launch_bounds__(256)
void k_fill64(const float* __restrict__ A, double* __restrict__ M)
{
  const int total = DIMN * DIMN;
  for (int idx = blockIdx.x * 256 + threadIdx.x; idx < total; idx += gridDim.x * 256) {
    double v = (double)A[idx];
    if ((idx >> 11) == (idx & 2047)) v += 1e-3;
    M[idx] = v;
  }
}

// ---------------- f32 GEMM: C = alpha*A*B + c1*E1 + c2*E2 + c3*E3 + dval*I ----------------
#define GBM 128
#define GBN 128
#define GBK 8
__global__ __launch_bounds__(256)
void k_gemm(const float* __restrict__ A, int lda,
            const float* __restrict__ B, int ldb,
            float* C, int ldc, int K, float alpha,
            const float* E1, int ld1, float c1,
            const float* E2, int ld2, float c2,
            const float* E3, int ld3, float c3,
            float dval)
{
  __shared__ float As[GBK][GBM];
  __shared__ float Bs[GBK][GBN];
  const int tid = threadIdx.x;
  const int tx = tid & 15, ty = tid >> 4;
  const int brow = blockIdx.y * GBM, bcol = blockIdx.x * GBN;

  const int arow = tid >> 1, ac0 = (tid & 1) * 4;   // A tile 128x8
  const int brw  = tid >> 5, bc0 = (tid & 31) * 4;  // B tile 8x128

  const float* Aptr = A + (size_t)(brow + arow) * lda + ac0;
  const float* Bptr = B + (size_t)brw * ldb + (bcol + bc0);

  float4 aPre = *(const float4*)Aptr;
  float4 bPre = *(const float4*)Bptr;

  float acc[8][8];
#pragma unroll
  for (int i = 0; i < 8; ++i)
#pragma unroll
    for (int j = 0; j < 8; ++j) acc[i][j] = 0.f;

  const int nk = K / GBK;
  for (int kt = 0; kt < nk; ++kt) {
    As[ac0 + 0][arow] = aPre.x;
    As[ac0 + 1][arow] = aPre.y;
    As[ac0 + 2][arow] = aPre.z;
    As[ac0 + 3][arow] = aPre.w;
    *(float4*)&Bs[brw][bc0] = bPre;
    __syncthreads();
    if (kt + 1 < nk) {
      aPre = *(const float4*)(Aptr + (size_t)(kt + 1) * GBK);
      bPre = *(const float4*)(Bptr + (size_t)(kt + 1) * GBK * ldb);
    }
#pragma unroll
    for (int kk = 0; kk < GBK; ++kk) {
      float a[8], b[8];
      *(float4*)&a[0] = *(const float4*)&As[kk][ty * 8];
      *(float4*)&a[4] = *(const float4*)&As[kk][ty * 8 + 4];
      *(float4*)&b[0] = *(const float4*)&Bs[kk][tx * 8];
      *(float4*)&b[4] = *(const float4*)&Bs[kk][tx * 8 + 4];
#pragma unroll
      for (int i = 0; i < 8; ++i)
#pragma unroll
        for (int j = 0; j < 8; ++j)
          acc[i][j] = fmaf(a[i], b[j], acc[i][j]);
    }
    __syncthreads();
  }
#pragma unroll
  for (int i = 0; i < 8; ++i) {
    const int gi = brow + ty * 8 + i;
#pragma unroll
    for (int j = 0; j < 8; ++j) {
      const int gj = bcol + tx * 8 + j;
      float v = alpha * acc[i][j];
      if (E1) v = fmaf(c1, E1[(size_t)gi * ld1 + gj], v);
      if (E2) v = fmaf(c2, E2[(size_t)gi * ld2 + gj], v);
      if (E3) v = fmaf(c3, E3[(size_t)gi * ld3 + gj], v);
      if (gi == gj) v += dval;
      C[(size_t)gi * ldc + gj] = v;
    }
  }
}

// ---------------- f64 GEMM (VALU, known-good): C = alpha*A*B + c1*E1 (64x64 tile) ----------------
#define DBM 64
#define DBK 8
__global__ __launch_bounds__(256)
void k_dgemm(const double* __restrict__ A, int lda,
             const double* __restrict__ B, int ldb,
             double* C, int ldc, int K, double alpha,
             const double* E1, int ld1, double c1, double dval)
{
  __shared__ double As[DBK][DBM];
  __shared__ double Bs[DBK][DBM];
  const int tid = threadIdx.x;
  const int tx = tid & 15, ty = tid >> 4;
  const int brow = blockIdx.y * DBM, bcol = blockIdx.x * DBM;

  const int arow = tid >> 2, ac0 = (tid & 3) * 2;   // A tile 64x8
  const int brw  = tid >> 5, bc0 = (tid & 31) * 2;  // B tile 8x64

  const double* Aptr = A + (size_t)(brow + arow) * lda + ac0;
  const double* Bptr = B + (size_t)brw * ldb + (bcol + bc0);

  double2 aPre = *(const double2*)Aptr;
  double2 bPre = *(const double2*)Bptr;

  double acc[4][4];
#pragma unroll
  for (int i = 0; i < 4; ++i)
#pragma unroll
    for (int j = 0; j < 4; ++j) acc[i][j] = 0.0;

  const int nk = K / DBK;
  for (int kt = 0; kt < nk; ++kt) {
    As[ac0 + 0][arow] = aPre.x;
    As[ac0 + 1][arow] = aPre.y;
    Bs[brw][bc0 + 0] = bPre.x;
    Bs[brw][bc0 + 1] = bPre.y;
    __syncthreads();
    if (kt + 1 < nk) {
      aPre = *(const double2*)(Aptr + (size_t)(kt + 1) * DBK);
      bPre = *(const double2*)(Bptr + (size_t)(kt + 1) * DBK * ldb);
    }
#pragma unroll
    for (int kk = 0; kk < DBK; ++kk) {
      double a[4], b[4];
#pragma unroll
      for (int i = 0; i < 4; ++i) a[i] = As[kk][ty * 4 + i];
#pragma unroll
      for (int j = 0; j < 4; ++j) b[j] = Bs[kk][tx * 4 + j];
#pragma unroll
      for (int i = 0; i < 4; ++i)
#pragma unroll
        for (int j = 0; j < 4; ++j)
          acc[i][j] = fma(a[i], b[j], acc[i][j]);
    }
    __syncthreads();
  }
#pragma unroll
  for (int i = 0; i < 4; ++i) {
    const int gi = brow + ty * 4 + i;
#pragma unroll
    for (int j = 0; j < 4; ++j) {
      const int gj = bcol + tx * 4 + j;
      double v = alpha * acc[i][j];
      if (E1) v = fma(c1, E1[(size_t)gi * ld1 + gj], v);
      if (gi == gj) v += dval;
      C[(size_t)gi * ldc + gj] = v;
    }
  }
}

// ---------------- transpose 2048x2048 f32 ----------------
__global__ __launch_bounds__(256)
void k_transpose(const float* __restrict__ in, float* __restrict__ out)
{
  __shared__ float t[32][33];
  const int bx = blockIdx.x * 32, by = blockIdx.y * 32;
  const int lx = threadIdx.x, ly = threadIdx.y; // (32,8)
  for (int dy = 0; dy < 32; dy += 8)
    t[ly + dy][lx] = in[(size_t)(by + ly + dy) * DIMN + bx + lx];
  __syncthreads();
  for (int dy = 0; dy < 32; dy += 8)
    out[(size_t)(bx + ly + dy) * DIMN + by + lx] = t[lx][ly + dy];
}

// ---------------- base case v2: invert 64x64 f64, partial pivoting, no row swap ----------------
// No-swap GJ: step p picks unused physical row rp = argmax |a[i][p]|; scale+eliminate.
// Row ops T give T[A|I] = [P|T] with P[rp,p]=1, so right-half physical row r_p = row p
// of A^-1: W[p][j] = a[r[p]][64+j]. 3 syncs/iter, races removed via register snapshots.
__global__ __launch_bounds__(1024)
void k_gj64(const double* __restrict__ M, int ldm, double* __restrict__ W, int ldw)
{
  __shared__ double a[64][130]; // [A | I]
  __shared__ double s_rpv;
  __shared__ int s_rp;
  __shared__ int s_used[64];
  __shared__ int s_r[64];
  const int tid = threadIdx.x;
  for (int idx = tid; idx < 64 * 64; idx += 1024) {
    const int r = idx >> 6, c = idx & 63;
    a[r][c] = M[(size_t)r * ldm + c];
    a[r][64 + c] = (r == c) ? 1.0 : 0.0;
  }
  if (tid < 64) s_used[tid] = 0;
  __syncthreads();

  const int c = tid & 127;   // column owned by this thread
  const int rg = tid >> 7;   // row group: rows [8rg, 8rg+8)

  for (int p = 0; p < 64; ++p) {
    // ---- phase A: wave 0 finds pivot row among unused ----
    if (tid < 64) {
      double v = s_used[tid] ? -1.0 : fabs(a[tid][p]);
      int bi = tid;
      for (int off = 32; off; off >>= 1) {
        const double ov = __shfl_down(v, off);
        const int oi = __shfl_down(bi, off);
        if (ov > v) { v = ov; bi = oi; }
      }
      if (tid == 0) {
        s_rp = bi; s_r[p] = bi; s_used[bi] = 1;
        s_rpv = 1.0 / a[bi][p];
      }
    }
    __syncthreads();
    // ---- phase B1: snapshot pivot row (scaled) + pivot column into registers ----
    const int rp = s_rp;
    const double prs = a[rp][c] * s_rpv;   // scaled pivot-row element for col c
    double pv[8];
#pragma unroll
    for (int k = 0; k < 8; ++k) pv[k] = a[rg * 8 + k][p];
    __syncthreads();
    // ---- phase B2: rank-1 update (owner-only writes) ----
#pragma unroll
    for (int k = 0; k < 8; ++k) {
      const int i = rg * 8 + k;
      a[i][c] = (i == rp) ? prs : fma(-pv[k], prs, a[i][c]);
    }
    __syncthreads();
  }

  for (int idx = tid; idx < 64 * 64; idx += 1024) {
    const int r = idx >> 6, cc = idx & 63;
    W[(size_t)r * ldw + cc] = a[s_r[r]][64 + cc];
  }
}

// ---------------- matvec f32 matrix, f64 vectors: vout = alpha*(Mat*vin) + vadd ----------------
__global__ __launch_bounds__(256)
void k_mv(const float* __restrict__ Mat, const double* __restrict__ vin,
          double* vout, const double* vadd, double alpha)
{
  const int lane = threadIdx.x & 63;
  const int row = blockIdx.x * 4 + (threadIdx.x >> 6);
  const float* mrow = Mat + (size_t)row * DIMN;
  double acc = 0.0;
  for (int p = 0; p < DIMN; p += 256) {
    const float4 m = *(const float4*)&mrow[p + lane * 4];
    const double* vp = &vin[p + lane * 4];
    acc += (double)m.x * vp[0] + (double)m.y * vp[1] + (double)m.z * vp[2] + (double)m.w * vp[3];
  }
  for (int off = 32; off; off >>= 1) acc += __shfl_down(acc, off);
  if (lane == 0) vout[row] = alpha * acc + (vadd ? vadd[row] : 0.0);
}

// ---------------- matvec f64 matrix: vout = alpha*(W*vin) + vadd ----------------
__global__ __launch_bounds__(256)
void k_mv64(const double* __restrict__ W, const double* __restrict__ vin,
            double* vout, const double* vadd, double alpha)
{
  const int lane = threadIdx.x & 63;
  const int row = blockIdx.x * 4 + (threadIdx.x >> 6);
  const double* mrow = W + (size_t)row * DIMN;
  double acc = 0.0;
  for (int p = 0; p < DIMN; p += 256) {
    const int idx = p + lane * 4;
    const double2 m0 = *(const double2*)&mrow[idx];
    const double2 m1 = *(const double2*)&mrow[idx + 2];
    acc += m0.x * vin[idx] + m0.y * vin[idx + 1] + m1.x * vin[idx + 2] + m1.y * vin[idx + 3];
  }
  for (int off = 32; off; off >>= 1) acc += __shfl_down(acc, off);
  if (lane == 0) vout[row] = alpha * acc + (vadd ? vadd[row] : 0.0);
}

// ---------------- residual: r = y - (A*x + 1e-3*x), A f32, vectors f64 ----------------
__global__ __launch_bounds__(256)
void k_mvres(const float* __restrict__ A, const double* __restrict__ x,
             const double* __restrict__ y, double* r)
{
  const int lane = threadIdx.x & 63;
  const int row = blockIdx.x * 4 + (threadIdx.x >> 6);
  const float* mrow = A + (size_t)row * DIMN;
  double acc = 0.0;
  for (int p = 0; p < DIMN; p += 256) {
    const float4 m = *(const float4*)&mrow[p + lane * 4];
    const double* vp = &x[p + lane * 4];
    acc += (double)m.x * vp[0] + (double)m.y * vp[1] + (double)m.z * vp[2] + (double)m.w * vp[3];
  }
  for (int off = 32; off; off >>= 1) acc += __shfl_down(acc, off);
  if (lane == 0) r[row] = y[row] - acc - 1e-3 * x[row];
}

// ---------------- one chain step: vout=(I+E)vin (blocks 0..511); uout=(I+ER^T)uin (512..1023) ----------------
__global__ __launch_bounds__(256)
void k_chain(const float* __restrict__ E, const float* __restrict__ vin, float* __restrict__ vout,
             const float* __restrict__ ERT, const float* __restrict__ uin, float* __restrict__ uout)
{
  const int lane = threadIdx.x & 63;
  const int w = threadIdx.x >> 6;
  const int b = blockIdx.x;
  const float* mrow; const float* xin; float* xout; int row;
  if (b < 512) { row = b * 4 + w; mrow = E + (size_t)row * DIMN; xin = vin; xout = vout; }
  else { row = (b - 512) * 4 + w; mrow = ERT + (size_t)row * DIMN; xin = uin; xout = uout; }
  float acc = 0.f;
  for (int p = 0; p < DIMN; p += 256) {
    const float4 m = *(const float4*)&mrow[p + lane * 4];
    const float* vp = &xin[p + lane * 4];
    acc = fmaf(m.x, vp[0], acc);
    acc = fmaf(m.y, vp[1], acc);
    acc = fmaf(m.z, vp[2], acc);
    acc = fmaf(m.w, vp[3], acc);
  }
  for (int off = 32; off; off >>= 1) acc += __shfl_down(acc, off);
  if (lane == 0) xout[row] = xin[row] + acc;
}

// ---------------- terms: out[8191-t] = dot(U[t/91], V[t%91]) ----------------
__global__ __launch_bounds__(256)
void k_terms(const float* __restrict__ U, const float* __restrict__ V, float* __restrict__ out)
{
  const int lane = threadIdx.x & 63;
  const int t = blockIdx.x * 4 + (threadIdx.x >> 6);
  const int j = t / RSPLIT, i = t - j * RSPLIT;
  const float* u = U + (size_t)j * DIMN;
  const float* v = V + (size_t)i * DIMN;
  float acc = 0.f;
  for (int p = 0; p < DIMN; p += 256) {
    const float4 a4 = *(const float4*)&u[p + lane * 4];
    const float4 b4 = *(const float4*)&v[p + lane * 4];
    acc = fmaf(a4.x, b4.x, acc); acc = fmaf(a4.y, b4.y, acc);
    acc = fmaf(a4.z, b4.z, acc); acc = fmaf(a4.w, b4.w, acc);
  }
  for (int off = 32; off; off >>= 1) acc += __shfl_down(acc, off);
  if (lane == 0) out[MSTEPS - 1 - t] = acc;
}

// ---------------- small vector inits ----------------
__global__ void k_vecinit(const float* __restrict__ B, double* __restrict__ b64,
                          const float* __restrict__ Cv, float* __restrict__ U0)
{
  const int i = blockIdx.x * 256 + threadIdx.x;
  if (i < DIMN) { b64[i] = 0.01 * (double)B[i]; U0[i] = Cv[i]; }
}
__global__ void k_v0(const double* __restrict__ x64, float* __restrict__ V0)
{
  const int i = blockIdx.x * 256 + threadIdx.x;
  if (i < DIMN) V0[i] = (float)x64[i];
}

// ---------------- host helpers ----------------
static inline void gemm(hipStream_t s, const float* A, int lda, const float* B, int ldb,
                        float* C, int ldc, int m, int n, int k, float alpha,
                        const float* E1 = nullptr, int ld1 = 0, float c1 = 0.f,
                        const float* E2 = nullptr, int ld2 = 0, float c2 = 0.f,
                        const float* E3 = nullptr, int ld3 = 0, float c3 = 0.f,
                        float dval = 0.f)
{
  dim3 grid(n / GBN, m / GBM), block(256);
  k_gemm<<<grid, block, 0, s>>>(A, lda, B, ldb, C, ldc, k, alpha,
                                E1, ld1, c1, E2, ld2, c2, E3, ld3, c3, dval);
}

static inline void dgemm(hipStream_t s, const double* A, int lda, const double* B, int ldb,
                         double* C, int ldc, int n, double alpha,
                         const double* E1 = nullptr, int ld1 = 0, double c1 = 0.0)
{
  dim3 grid(n / DBM, n / DBM), block(256);
  k_dgemm<<<grid, block, 0, s>>>(A, lda, B, ldb, C, ldc, n, alpha, E1, ld1, c1, 0.0);
}

// f64 block-Schur inversion. Destroys M (S over M22, U over M21). scr holds T (h^2/level).
static void invert_rec64(hipStream_t s, double* M, int ldm, double* W, int ldw, int n, double* scr)
{
  if (n == 64) { k_gj64<<<dim3(1), dim3(1024), 0, s>>>(M, ldm, W, ldw); return; }
  const int h = n / 2;
  double* T = scr;
  double* deeper = scr + (size_t)h * h;
  double* M12 = M + h;
  double* M21 = M + (size_t)h * ldm;
  double* M22 = M + (size_t)h * ldm + h;
  double* W11 = W;
  double* W12 = W + h;
  double* W21 = W + (size_t)h * ldw;
  double* W22 = W + (size_t)h * ldw + h;
  invert_rec64(s, M, ldm, W11, ldw, h, deeper);
  dgemm(s, M21, ldm, W11, ldw, T, h, h, 1.0);                      // T = M21*W11
  dgemm(s, T, h, M12, ldm, M22, ldm, h, -1.0, M22, ldm, 1.0);      // S = M22 - T*M12 (in place)
  invert_rec64(s, M22, ldm, W22, ldw, h, deeper);                  // W22 = inv(S)
  dgemm(s, W11, ldw, M12, ldm, M21, ldm, h, 1.0);                  // U = W11*M12 (over dead M21)
  dgemm(s, M21, ldm, W22, ldw, W12, ldw, h, -1.0);                 // W12 = -U*W22
  dgemm(s, W22, ldw, T, h, W21, ldw, h, -1.0);                     // W21 = -W22*T
  dgemm(s, W12, ldw, T, h, W11, ldw, h, -1.0, W11, ldw, 1.0);      // W11 -= W12*T
}

extern "C" void kernel_launch(void* const* d_in, const int* in_sizes, int n_in,
                              void* d_out, int out_size, void* d_ws, size_t ws_size,
                              hipStream_t stream)
{
  const float* dA = (const float*)d_in[0];
  const float* dB = (const float*)d_in[1];
  const float* dC = (const float*)d_in[2];
  float* out = (float*)d_out;

  // Arena layout (floats): Ebuf | t1 | t2 | t3 | t4 | scr64(2*SCRD) | vecs
  float* fb = (float*)d_ws;
  float* Ebuf = fb;                 // E = exp(0.01A) - I            (f32, persistent)
  float* t1 = fb + NN;              // Y2      | M64 low half
  float* t2 = t1 + NN;              //         | M64 high half
  float* t3 = t2 + NN;              // H/ERT   | W64 low half
  float* t4 = t3 + NN;              // ER      | W64 high half
  double* M64 = (double*)t1;        // spans t1,t2 (32MB)
  double* W64 = (double*)t3;        // spans t3,t4 (32MB)
  double* scr64 = (double*)(fb + 5 * NN);
  double* y64 = scr64 + SCRD;
  double* x64 = y64 + DIMN;
  double* r64 = x64 + DIMN;
  double* b64 = r64 + DIMN;
  float* V  = (float*)(b64 + DIMN);            // 91 x 2048 (A^i * Bbar rows)
  float* Uc = V + (size_t)RSPLIT * DIMN;       // 91 x 2048 (C * AR^j rows)

  const size_t needed = (5 * NN + 2 * SCRD) * 4 + 4 * (size_t)DIMN * 8
                        + (size_t)(2 * RSPLIT) * DIMN * 4;
  if (ws_size < needed) return; // clean zero-output failure instead of OOB

  const float* NUL = nullptr;
  dim3 cb(256), cg(2048);

  // ---- Phase 1: W64 = inv(A + 1e-3 I) in f64 (destroys M64) ----
  k_fill64<<<cg, cb, 0, stream>>>(dA, M64);
  invert_rec64(stream, M64, DIMN, W64, DIMN, DIMN, scr64);

  // ---- Phase 2: E = exp(0.01A) - I, deg-2: E = (1e-4/2)A^2 + 0.01A ----
  gemm(stream, dA, DIMN, dA, DIMN, Ebuf, DIMN, DIMN, DIMN, DIMN, 5e-5f,
       dA, DIMN, 0.01f);

  // ---- Phase 3: Bbar via y = E*(0.01B); x = W*y; 2x f64 iterative refinement ----
  k_vecinit<<<dim3(8), cb, 0, stream>>>(dB, b64, dC, Uc);                      // b64=0.01B, U[0]=C
  k_mv<<<dim3(512), cb, 0, stream>>>(Ebuf, b64, y64, (const double*)nullptr, 1.0);
  k_mv64<<<dim3(512), cb, 0, stream>>>(W64, y64, x64, (const double*)nullptr, 1.0);
  for (int it = 0; it < 2; ++it) {
    k_mvres<<<dim3(512), cb, 0, stream>>>(dA, x64, y64, r64);                  // r = y - (A+1e-3I)x
    k_mv64<<<dim3(512), cb, 0, stream>>>(W64, r64, x64, x64, 1.0);             // x += W*r
  }
  k_v0<<<dim3(8), cb, 0, stream>>>(x64, V);                                    // V[0] = Bbar

  // ---- Phase 4: ER = exp(0.91A) - I, deg-4 PS (W64 dead now), Y = 0.91A ----
  // Y2 -> t1; H = Y/6 + Y2/24 -> t3; ER = Y2*H + Y2/2 + Y -> t4
  gemm(stream, dA, DIMN, dA, DIMN, t1, DIMN, DIMN, DIMN, DIMN, 0.8281f);       // Y2 = (0.91A)^2
  k_combine4<<<cg, cb, 0, stream>>>(t3, dA, 0.91f / 6.f, t1, 1.f / 24.f,
                                    NUL, 0, NUL, 0, 0.f);                      // H
  gemm(stream, t1, DIMN, t3, DIMN, t4, DIMN, DIMN, DIMN, DIMN, 1.f,
       t1, DIMN, 0.5f, dA, DIMN, 0.91f);                                       // ER
  k_transpose<<<dim3(64, 64), dim3(32, 8), 0, stream>>>(t4, t3);               // ERT -> t3

  // ---- Phase 5: balanced serial chains (90 steps each, concurrent) + terms ----
  for (int s = 0; s < NSTEPS; ++s) {
    k_chain<<<dim3(1024), cb, 0, stream>>>(Ebuf, V + (size_t)s * DIMN, V + (size_t)(s + 1) * DIMN,
                                           t3, Uc + (size_t)s * DIMN, Uc + (size_t)(s + 1) * DIMN);
  }
  k_terms<<<dim3(2048), cb, 0, stream>>>(Uc, V, out);
}

// Round 6
// 5200.171 us; speedup vs baseline: 1.7077x; 1.4560x over previous
//
#include <hip/hip_runtime.h>

// ZOH linear layer: K[1,8192], dim 2048.
// Y2=(0.91A)^2 (1 f32 GEMM); E=expm(.01A)-I = c*Y2+0.01A (elementwise);
// ER=expm(0.91A)-I deg-4 PS (1 more f32 GEMM);
// W=inv(A+1e-3 I) in f64 IN-PLACE: flat blocked Gauss-Jordan, 32 stages of
// 64-wide pivot blocks (block-local pivoting via k_gj64; wide trailing GEMMs)
// + 2x f64 iterative refinement on the single solve vector.
// K[91j+i] = (C*AR^j)·(A^i*Bbar): two balanced serial matvec chains (90 steps) + dots.
// Arena ~96MB: Ebuf | t1 t2 (=M64, becomes inv in place; then ER/ERT f32) | t3 t4 | scr64 | vecs.

#define DIMN 2048
#define MSTEPS 8192
#define RSPLIT 91          // sqrt split: t = 91j + i, i,j in [0,91)
#define NSTEPS 90          // serial chain steps for each of V and U
#define NN ((size_t)DIMN * DIMN)
#define SCRD ((size_t)(1024*1024 + 512*512 + 256*256 + 128*128 + 64*64))
#define NBLK 32            // 2048 / 64 pivot blocks

// ---------------- elementwise f32: out = c1*i1+c2*i2+c3*i3+c4*i4 + dval*I ----------------
__global__ __launch_bounds__(256)
void k_combine4(float* out,
                const float* i1, float c1, const float* i2, float c2,
                const float* i3, float c3, const float* i4, float c4,
                float dval)
{
  const int total = DIMN * DIMN;
  for (int idx = blockIdx.x * 256 + threadIdx.x; idx < total; idx += gridDim.x * 256) {
    float v = 0.f;
    if (i1) v = fmaf(c1, i1[idx], v);
    if (i2) v = fmaf(c2, i2[idx], v);
    if (i3) v = fmaf(c3, i3[idx], v);
    if (i4) v = fmaf(c4, i4[idx], v);
    if ((idx >> 11) == (idx & 2047)) v += dval;
    out[idx] = v;
  }
}

// ---------------- M64 = (double)A + 1e-3 I ----------------
__global__ __launch_bounds__(256)
void k_fill64(const float* __restrict__ A, double* __restrict__ M)
{
  const int total = DIMN * DIMN;
  for (int idx = blockIdx.x * 256 + threadIdx.x; idx < total; idx += gridDim.x * 256) {
    double v = (double)A[idx];
    if ((idx >> 11) == (idx & 2047)) v += 1e-3;
    M[idx] = v;
  }
}

// ---------------- f32 GEMM: C = alpha*A*B + c1*E1 + c2*E2 + c3*E3 + dval*I ----------------
#define GBM 128
#define GBN 128
#define GBK 8
__global__ __launch_bounds__(256)
void k_gemm(const float* __restrict__ A, int lda,
            const float* __restrict__ B, int ldb,
            float* C, int ldc, int K, float alpha,
            const float* E1, int ld1, float c1,
            const float* E2, int ld2, float c2,
            const float* E3, int ld3, float c3,
            float dval)
{
  __shared__ float As[GBK][GBM];
  __shared__ float Bs[GBK][GBN];
  const int tid = threadIdx.x;
  const int tx = tid & 15, ty = tid >> 4;
  const int brow = blockIdx.y * GBM, bcol = blockIdx.x * GBN;

  const int arow = tid >> 1, ac0 = (tid & 1) * 4;   // A tile 128x8
  const int brw  = tid >> 5, bc0 = (tid & 31) * 4;  // B tile 8x128

  const float* Aptr = A + (size_t)(brow + arow) * lda + ac0;
  const float* Bptr = B + (size_t)brw * ldb + (bcol + bc0);

  float4 aPre = *(const float4*)Aptr;
  float4 bPre = *(const float4*)Bptr;

  float acc[8][8];
#pragma unroll
  for (int i = 0; i < 8; ++i)
#pragma unroll
    for (int j = 0; j < 8; ++j) acc[i][j] = 0.f;

  const int nk = K / GBK;
  for (int kt = 0; kt < nk; ++kt) {
    As[ac0 + 0][arow] = aPre.x;
    As[ac0 + 1][arow] = aPre.y;
    As[ac0 + 2][arow] = aPre.z;
    As[ac0 + 3][arow] = aPre.w;
    *(float4*)&Bs[brw][bc0] = bPre;
    __syncthreads();
    if (kt + 1 < nk) {
      aPre = *(const float4*)(Aptr + (size_t)(kt + 1) * GBK);
      bPre = *(const float4*)(Bptr + (size_t)(kt + 1) * GBK * ldb);
    }
#pragma unroll
    for (int kk = 0; kk < GBK; ++kk) {
      float a[8], b[8];
      *(float4*)&a[0] = *(const float4*)&As[kk][ty * 8];
      *(float4*)&a[4] = *(const float4*)&As[kk][ty * 8 + 4];
      *(float4*)&b[0] = *(const float4*)&Bs[kk][tx * 8];
      *(float4*)&b[4] = *(const float4*)&Bs[kk][tx * 8 + 4];
#pragma unroll
      for (int i = 0; i < 8; ++i)
#pragma unroll
        for (int j = 0; j < 8; ++j)
          acc[i][j] = fmaf(a[i], b[j], acc[i][j]);
    }
    __syncthreads();
  }
#pragma unroll
  for (int i = 0; i < 8; ++i) {
    const int gi = brow + ty * 8 + i;
#pragma unroll
    for (int j = 0; j < 8; ++j) {
      const int gj = bcol + tx * 8 + j;
      float v = alpha * acc[i][j];
      if (E1) v = fmaf(c1, E1[(size_t)gi * ld1 + gj], v);
      if (E2) v = fmaf(c2, E2[(size_t)gi * ld2 + gj], v);
      if (E3) v = fmaf(c3, E3[(size_t)gi * ld3 + gj], v);
      if (gi == gj) v += dval;
      C[(size_t)gi * ldc + gj] = v;
    }
  }
}

// ---------------- f64 GEMM (VALU): C = alpha*A*B + c1*E1 (64x64 tile, K mult of 8) ----------------
#define DBM 64
#define DBK 8
__global__ __launch_bounds__(256)
void k_dgemm(const double* __restrict__ A, int lda,
             const double* __restrict__ B, int ldb,
             double* C, int ldc, int K, double alpha,
             const double* E1, int ld1, double c1)
{
  __shared__ double As[DBK][DBM];
  __shared__ double Bs[DBK][DBM];
  const int tid = threadIdx.x;
  const int tx = tid & 15, ty = tid >> 4;
  const int brow = blockIdx.y * DBM, bcol = blockIdx.x * DBM;

  const int arow = tid >> 2, ac0 = (tid & 3) * 2;   // A tile 64x8
  const int brw  = tid >> 5, bc0 = (tid & 31) * 2;  // B tile 8x64

  const double* Aptr = A + (size_t)(brow + arow) * lda + ac0;
  const double* Bptr = B + (size_t)brw * ldb + (bcol + bc0);

  double2 aPre = *(const double2*)Aptr;
  double2 bPre = *(const double2*)Bptr;

  double acc[4][4];
#pragma unroll
  for (int i = 0; i < 4; ++i)
#pragma unroll
    for (int j = 0; j < 4; ++j) acc[i][j] = 0.0;

  const int nk = K / DBK;
  for (int kt = 0; kt < nk; ++kt) {
    As[ac0 + 0][arow] = aPre.x;
    As[ac0 + 1][arow] = aPre.y;
    Bs[brw][bc0 + 0] = bPre.x;
    Bs[brw][bc0 + 1] = bPre.y;
    __syncthreads();
    if (kt + 1 < nk) {
      aPre = *(const double2*)(Aptr + (size_t)(kt + 1) * DBK);
      bPre = *(const double2*)(Bptr + (size_t)(kt + 1) * DBK * ldb);
    }
#pragma unroll
    for (int kk = 0; kk < DBK; ++kk) {
      double a[4], b[4];
#pragma unroll
      for (int i = 0; i < 4; ++i) a[i] = As[kk][ty * 4 + i];
#pragma unroll
      for (int j = 0; j < 4; ++j) b[j] = Bs[kk][tx * 4 + j];
#pragma unroll
      for (int i = 0; i < 4; ++i)
#pragma unroll
        for (int j = 0; j < 4; ++j)
          acc[i][j] = fma(a[i], b[j], acc[i][j]);
    }
    __syncthreads();
  }
#pragma unroll
  for (int i = 0; i < 4; ++i) {
    const int gi = brow + ty * 4 + i;
#pragma unroll
    for (int j = 0; j < 4; ++j) {
      const int gj = bcol + tx * 4 + j;
      double v = alpha * acc[i][j];
      if (E1) v = fma(c1, E1[(size_t)gi * ld1 + gj], v);
      C[(size_t)gi * ldc + gj] = v;
    }
  }
}

// ---------------- transpose 2048x2048 f32 ----------------
__global__ __launch_bounds__(256)
void k_transpose(const float* __restrict__ in, float* __restrict__ out)
{
  __shared__ float t[32][33];
  const int bx = blockIdx.x * 32, by = blockIdx.y * 32;
  const int lx = threadIdx.x, ly = threadIdx.y; // (32,8)
  for (int dy = 0; dy < 32; dy += 8)
    t[ly + dy][lx] = in[(size_t)(by + ly + dy) * DIMN + bx + lx];
  __syncthreads();
  for (int dy = 0; dy < 32; dy += 8)
    out[(size_t)(bx + ly + dy) * DIMN + by + lx] = t[lx][ly + dy];
}

// ---------------- base case: invert 64x64 f64, partial pivoting, no row swap ----------------
__global__ __launch_bounds__(1024)
void k_gj64(const double* __restrict__ M, int ldm, double* __restrict__ W, int ldw)
{
  __shared__ double a[64][130]; // [A | I]
  __shared__ double s_rpv;
  __shared__ int s_rp;
  __shared__ int s_used[64];
  __shared__ int s_r[64];
  const int tid = threadIdx.x;
  for (int idx = tid; idx < 64 * 64; idx += 1024) {
    const int r = idx >> 6, c = idx & 63;
    a[r][c] = M[(size_t)r * ldm + c];
    a[r][64 + c] = (r == c) ? 1.0 : 0.0;
  }
  if (tid < 64) s_used[tid] = 0;
  __syncthreads();

  const int c = tid & 127;   // column owned by this thread
  const int rg = tid >> 7;   // row group: rows [8rg, 8rg+8)

  for (int p = 0; p < 64; ++p) {
    if (tid < 64) {
      double v = s_used[tid] ? -1.0 : fabs(a[tid][p]);
      int bi = tid;
      for (int off = 32; off; off >>= 1) {
        const double ov = __shfl_down(v, off);
        const int oi = __shfl_down(bi, off);
        if (ov > v) { v = ov; bi = oi; }
      }
      if (tid == 0) {
        s_rp = bi; s_r[p] = bi; s_used[bi] = 1;
        s_rpv = 1.0 / a[bi][p];
      }
    }
    __syncthreads();
    const int rp = s_rp;
    const double prs = a[rp][c] * s_rpv;
    double pv[8];
#pragma unroll
    for (int k = 0; k < 8; ++k) pv[k] = a[rg * 8 + k][p];
    __syncthreads();
#pragma unroll
    for (int k = 0; k < 8; ++k) {
      const int i = rg * 8 + k;
      a[i][c] = (i == rp) ? prs : fma(-pv[k], prs, a[i][c]);
    }
    __syncthreads();
  }

  for (int idx = tid; idx < 64 * 64; idx += 1024) {
    const int r = idx >> 6, cc = idx & 63;
    W[(size_t)r * ldw + cc] = a[s_r[r]][64 + cc];
  }
}

// ---------------- GJ stage fixups ----------------
// After rowscale (Rpan = Dinv * M[prows][:], so Rpan[pcols] = I):
// M[prows][:] = Rpan with pivot-block cols := Dinv; also patch Rpan[pcols] := Dinv.
__global__ __launch_bounds__(256)
void k_setrow(double* __restrict__ Rpan, const double* __restrict__ Dinv,
              double* __restrict__ M, int p)
{
  const int idx = blockIdx.x * 256 + threadIdx.x;   // 64*2048 total, grid 512
  const int r = idx >> 11, c = idx & 2047;
  double v;
  if ((c >> 6) == p) {
    v = Dinv[r * 64 + (c & 63)];
    Rpan[(size_t)r * DIMN + c] = v;
  } else {
    v = Rpan[(size_t)r * DIMN + c];
  }
  M[(size_t)(p * 64 + r) * DIMN + c] = v;
}

// Cpan[i][k] = (i in prows) ? 0 : M[i][pcols+k]; zero M's pivot column for non-pivot rows.
__global__ __launch_bounds__(256)
void k_colprep(double* __restrict__ Cpan, double* __restrict__ M, int p)
{
  const int idx = blockIdx.x * 256 + threadIdx.x;   // 2048*64 total, grid 512
  const int i = idx >> 6, k = idx & 63;
  const bool inP = (i >> 6) == p;
  const size_t mo = (size_t)i * DIMN + p * 64 + k;
  double v = 0.0;
  if (!inP) { v = M[mo]; M[mo] = 0.0; }
  Cpan[idx] = v;
}

// ---------------- matvec f32 matrix, f64 vectors: vout = alpha*(Mat*vin) + vadd ----------------
__global__ __launch_bounds__(256)
void k_mv(const float* __restrict__ Mat, const double* __restrict__ vin,
          double* vout, const double* vadd, double alpha)
{
  const int lane = threadIdx.x & 63;
  const int row = blockIdx.x * 4 + (threadIdx.x >> 6);
  const float* mrow = Mat + (size_t)row * DIMN;
  double acc = 0.0;
  for (int p = 0; p < DIMN; p += 256) {
    const float4 m = *(const float4*)&mrow[p + lane * 4];
    const double* vp = &vin[p + lane * 4];
    acc += (double)m.x * vp[0] + (double)m.y * vp[1] + (double)m.z * vp[2] + (double)m.w * vp[3];
  }
  for (int off = 32; off; off >>= 1) acc += __shfl_down(acc, off);
  if (lane == 0) vout[row] = alpha * acc + (vadd ? vadd[row] : 0.0);
}

// ---------------- matvec f64 matrix: vout = alpha*(W*vin) + vadd ----------------
__global__ __launch_bounds__(256)
void k_mv64(const double* __restrict__ W, const double* __restrict__ vin,
            double* vout, const double* vadd, double alpha)
{
  const int lane = threadIdx.x & 63;
  const int row = blockIdx.x * 4 + (threadIdx.x >> 6);
  const double* mrow = W + (size_t)row * DIMN;
  double acc = 0.0;
  for (int p = 0; p < DIMN; p += 256) {
    const int idx = p + lane * 4;
    const double2 m0 = *(const double2*)&mrow[idx];
    const double2 m1 = *(const double2*)&mrow[idx + 2];
    acc += m0.x * vin[idx] + m0.y * vin[idx + 1] + m1.x * vin[idx + 2] + m1.y * vin[idx + 3];
  }
  for (int off = 32; off; off >>= 1) acc += __shfl_down(acc, off);
  if (lane == 0) vout[row] = alpha * acc + (vadd ? vadd[row] : 0.0);
}

// ---------------- residual: r = y - (A*x + 1e-3*x), A f32, vectors f64 ----------------
__global__ __launch_bounds__(256)
void k_mvres(const float* __restrict__ A, const double* __restrict__ x,
             const double* __restrict__ y, double* r)
{
  const int lane = threadIdx.x & 63;
  const int row = blockIdx.x * 4 + (threadIdx.x >> 6);
  const float* mrow = A + (size_t)row * DIMN;
  double acc = 0.0;
  for (int p = 0; p < DIMN; p += 256) {
    const float4 m = *(const float4*)&mrow[p + lane * 4];
    const double* vp = &x[p + lane * 4];
    acc += (double)m.x * vp[0] + (double)m.y * vp[1] + (double)m.z * vp[2] + (double)m.w * vp[3];
  }
  for (int off = 32; off; off >>= 1) acc += __shfl_down(acc, off);
  if (lane == 0) r[row] = y[row] - acc - 1e-3 * x[row];
}

// ---------------- one chain step: vout=(I+E)vin (blocks 0..511); uout=(I+ER^T)uin (512..1023) ----------------
__global__ __launch_bounds__(256)
void k_chain(const float* __restrict__ E, const float* __restrict__ vin, float* __restrict__ vout,
             const float* __restrict__ ERT, const float* __restrict__ uin, float* __restrict__ uout)
{
  const int lane = threadIdx.x & 63;
  const int w = threadIdx.x >> 6;
  const int b = blockIdx.x;
  const float* mrow; const float* xin; float* xout; int row;
  if (b < 512) { row = b * 4 + w; mrow = E + (size_t)row * DIMN; xin = vin; xout = vout; }
  else { row = (b - 512) * 4 + w; mrow = ERT + (size_t)row * DIMN; xin = uin; xout = uout; }
  float acc = 0.f;
  for (int p = 0; p < DIMN; p += 256) {
    const float4 m = *(const float4*)&mrow[p + lane * 4];
    const float* vp = &xin[p + lane * 4];
    acc = fmaf(m.x, vp[0], acc);
    acc = fmaf(m.y, vp[1], acc);
    acc = fmaf(m.z, vp[2], acc);
    acc = fmaf(m.w, vp[3], acc);
  }
  for (int off = 32; off; off >>= 1) acc += __shfl_down(acc, off);
  if (lane == 0) xout[row] = xin[row] + acc;
}

// ---------------- terms: out[8191-t] = dot(U[t/91], V[t%91]) ----------------
__global__ __launch_bounds__(256)
void k_terms(const float* __restrict__ U, const float* __restrict__ V, float* __restrict__ out)
{
  const int lane = threadIdx.x & 63;
  const int t = blockIdx.x * 4 + (threadIdx.x >> 6);
  const int j = t / RSPLIT, i = t - j * RSPLIT;
  const float* u = U + (size_t)j * DIMN;
  const float* v = V + (size_t)i * DIMN;
  float acc = 0.f;
  for (int p = 0; p < DIMN; p += 256) {
    const float4 a4 = *(const float4*)&u[p + lane * 4];
    const float4 b4 = *(const float4*)&v[p + lane * 4];
    acc = fmaf(a4.x, b4.x, acc); acc = fmaf(a4.y, b4.y, acc);
    acc = fmaf(a4.z, b4.z, acc); acc = fmaf(a4.w, b4.w, acc);
  }
  for (int off = 32; off; off >>= 1) acc += __shfl_down(acc, off);
  if (lane == 0) out[MSTEPS - 1 - t] = acc;
}

// ---------------- small vector inits ----------------
__global__ void k_vecinit(const float* __restrict__ B, double* __restrict__ b64,
                          const float* __restrict__ Cv, float* __restrict__ U0)
{
  const int i = blockIdx.x * 256 + threadIdx.x;
  if (i < DIMN) { b64[i] = 0.01 * (double)B[i]; U0[i] = Cv[i]; }
}
__global__ void k_v0(const double* __restrict__ x64, float* __restrict__ V0)
{
  const int i = blockIdx.x * 256 + threadIdx.x;
  if (i < DIMN) V0[i] = (float)x64[i];
}

// ---------------- host helpers ----------------
static inline void gemm(hipStream_t s, const float* A, int lda, const float* B, int ldb,
                        float* C, int ldc, int m, int n, int k, float alpha,
                        const float* E1 = nullptr, int ld1 = 0, float c1 = 0.f,
                        const float* E2 = nullptr, int ld2 = 0, float c2 = 0.f,
                        const float* E3 = nullptr, int ld3 = 0, float c3 = 0.f,
                        float dval = 0.f)
{
  dim3 grid(n / GBN, m / GBM), block(256);
  k_gemm<<<grid, block, 0, s>>>(A, lda, B, ldb, C, ldc, k, alpha,
                                E1, ld1, c1, E2, ld2, c2, E3, ld3, c3, dval);
}

// Flat blocked Gauss-Jordan inversion in place: M <- inv(M). f64.
// 32 stages; per stage: gj64 -> rowscale GEMM -> setrow -> colprep -> trailing GEMM.
static void invert_gj64(hipStream_t s, double* M, double* Dinv, double* Cpan, double* Rpan)
{
  for (int p = 0; p < NBLK; ++p) {
    double* Mrow = M + (size_t)p * 64 * DIMN;
    k_gj64<<<dim3(1), dim3(1024), 0, s>>>(Mrow + p * 64, DIMN, Dinv, 64);
    // Rpan = Dinv * M[prows][:]
    k_dgemm<<<dim3(32, 1), dim3(256), 0, s>>>(Dinv, 64, Mrow, DIMN, Rpan, DIMN, 64, 1.0,
                                              nullptr, 0, 0.0);
    k_setrow<<<dim3(512), dim3(256), 0, s>>>(Rpan, Dinv, M, p);
    k_colprep<<<dim3(512), dim3(256), 0, s>>>(Cpan, M, p);
    // trailing: M = M - Cpan * Rpan (rows in pivot block have Cpan = 0 -> unchanged)
    k_dgemm<<<dim3(32, 32), dim3(256), 0, s>>>(Cpan, 64, Rpan, DIMN, M, DIMN, 64, -1.0,
                                               M, DIMN, 1.0);
  }
}

extern "C" void kernel_launch(void* const* d_in, const int* in_sizes, int n_in,
                              void* d_out, int out_size, void* d_ws, size_t ws_size,
                              hipStream_t stream)
{
  const float* dA = (const float*)d_in[0];
  const float* dB = (const float*)d_in[1];
  const float* dC = (const float*)d_in[2];
  float* out = (float*)d_out;

  // Arena layout (floats): Ebuf | t1 | t2 | t3 | t4 | scr64(2*SCRD) | vecs
  float* fb = (float*)d_ws;
  float* Ebuf = fb;                 // E = exp(0.01A) - I  (f32, persistent)
  float* t1 = fb + NN;              // W64 low  | later ER (f32)
  float* t2 = t1 + NN;              // W64 high | later ERT (f32)
  float* t3 = t2 + NN;              // Y2 (f32)
  float* t4 = t3 + NN;              // H  (f32)
  double* M64 = (double*)t1;        // spans t1,t2 (32MB); becomes inv in place
  double* scr64 = (double*)(fb + 5 * NN);
  double* Dinv = scr64;                        // 64x64
  double* Cpan = Dinv + 64 * 64;               // 2048x64
  double* Rpan = Cpan + (size_t)DIMN * 64;     // 64x2048
  double* y64 = Rpan + (size_t)DIMN * 64;
  double* x64 = y64 + DIMN;
  double* r64 = x64 + DIMN;
  double* b64 = r64 + DIMN;
  float* V  = (float*)(b64 + DIMN);            // 91 x 2048 (A^i * Bbar rows)
  float* Uc = V + (size_t)RSPLIT * DIMN;       // 91 x 2048 (C * AR^j rows)

  const size_t needed = 5 * NN * 4
                        + (64 * 64 + 2 * (size_t)DIMN * 64 + 4 * (size_t)DIMN) * 8
                        + (size_t)(2 * RSPLIT) * DIMN * 4;
  if (ws_size < needed) return; // clean zero-output failure instead of OOB

  const float* NUL = nullptr;
  dim3 cb(256), cg(2048);

  // ---- Phase 1: M64 = A + 1e-3 I; invert in place (flat blocked GJ, f64) ----
  k_fill64<<<cg, cb, 0, stream>>>(dA, M64);
  invert_gj64(stream, M64, Dinv, Cpan, Rpan);

  // ---- Phase 2: Y2 = (0.91A)^2; E = (5e-5/0.8281)*Y2 + 0.01*A ----
  gemm(stream, dA, DIMN, dA, DIMN, t3, DIMN, DIMN, DIMN, DIMN, 0.8281f);       // Y2
  k_combine4<<<cg, cb, 0, stream>>>(Ebuf, t3, (float)(5e-5 / 0.8281), dA, 0.01f,
                                    NUL, 0, NUL, 0, 0.f);                      // E

  // ---- Phase 3: Bbar via y = E*(0.01B); x = W*y; 2x f64 iterative refinement ----
  k_vecinit<<<dim3(8), cb, 0, stream>>>(dB, b64, dC, Uc);                      // b64=0.01B, U[0]=C
  k_mv<<<dim3(512), cb, 0, stream>>>(Ebuf, b64, y64, (const double*)nullptr, 1.0);
  k_mv64<<<dim3(512), cb, 0, stream>>>(M64, y64, x64, (const double*)nullptr, 1.0);
  for (int it = 0; it < 2; ++it) {
    k_mvres<<<dim3(512), cb, 0, stream>>>(dA, x64, y64, r64);                  // r = y - (A+1e-3I)x
    k_mv64<<<dim3(512), cb, 0, stream>>>(M64, r64, x64, x64, 1.0);             // x += W*r
  }
  k_v0<<<dim3(8), cb, 0, stream>>>(x64, V);                                    // V[0] = Bbar

  // ---- Phase 4: ER = exp(0.91A) - I, deg-4 PS (M64/W dead now), Y = 0.91A ----
  // H = Y/6 + Y2/24 -> t4; ER = Y2*H + Y2/2 + Y -> t1; ERT -> t2
  k_combine4<<<cg, cb, 0, stream>>>(t4, dA, 0.91f / 6.f, t3, 1.f / 24.f,
                                    NUL, 0, NUL, 0, 0.f);                      // H
  gemm(stream, t3, DIMN, t4, DIMN, t1, DIMN, DIMN, DIMN, DIMN, 1.f,
       t3, DIMN, 0.5f, dA, DIMN, 0.91f);                                      // ER
  k_transpose<<<dim3(64, 64), dim3(32, 8), 0, stream>>>(t1, t2);               // ERT

  // ---- Phase 5: balanced serial chains (90 steps each, concurrent) + terms ----
  for (int s = 0; s < NSTEPS; ++s) {
    k_chain<<<dim3(1024), cb, 0, stream>>>(Ebuf, V + (size_t)s * DIMN, V + (size_t)(s + 1) * DIMN,
                                           t2, Uc + (size_t)s * DIMN, Uc + (size_t)(s + 1) * DIMN);
  }
  k_terms<<<dim3(2048), cb, 0, stream>>>(Uc, V, out);
}